// Round 4
// baseline (2654.429 us; speedup 1.0000x reference)
//
#include <hip/hip_runtime.h>
#include <math.h>

// ---------------------------------------------------------------------------
// MultiTemporalCrossTransformer — factorized algorithm, round 4.
//   * projections via bf16 MFMA GEMM (frame-factorized: 900x6912x1152)
//   * LN stats from per-frame means + fp32 self-Gram
//   * scores via MFMA:  24*score = rq * (Eq_aug . Kmat^T) + vconst
//       Eq_aug[16 x 40] : rows t: 1 at a_i(t); zgq; mq; zbq-mq*Gbh
//       Kmat [224 x 40] : rows e: rk*GGcol(a); -rk*mk; rk*(mk*Ggh-zgk); 1
//   * softmax in C-fragment layout (shfl_xor + tiny LDS exchange)
//   * marginalization via MFMA: M[16x36] = P[16x224] . L[224x36] per shot
//   * PV + fused distance (unchanged structure)
// ---------------------------------------------------------------------------

#define DIM 1152
#define HDIM 576
#define NTUP 220
#define CHUNK 16

typedef __attribute__((ext_vector_type(4))) float f32x4;
typedef __attribute__((ext_vector_type(8))) short short8;

__device__ __forceinline__ ushort f2bf(float x) {
  union { float f; unsigned u; } v; v.f = x;
  unsigned r = (v.u + 0x7FFFu + ((v.u >> 16) & 1u)) >> 16;
  return (ushort)r;
}
__device__ __forceinline__ float bf2f(ushort x) {
  union { unsigned u; float f; } v; v.u = ((unsigned)x) << 16;
  return v.f;
}

// ---------------- init: tuple tables, g/b constants ------------------------
__global__ __launch_bounds__(256) void init_tables(
    const float* __restrict__ g, const float* __restrict__ bb,
    int* __restrict__ tup, uint* __restrict__ tupP, float* __restrict__ consts)
{
  const int tid = threadIdx.x;
  if (tid < 220) {
    int t = tid, idx = 0;
    for (int a = 0; a < 10; a++)
      for (int b2 = a + 1; b2 < 11; b2++)
        for (int c = b2 + 1; c < 12; c++) {
          if (idx == t) {
            tup[t*3+0]=a; tup[t*3+1]=b2; tup[t*3+2]=c;
            tupP[t] = (uint)a | ((uint)b2 << 8) | ((uint)c << 16);
          }
          idx++;
        }
  }
  __shared__ float rd[6];
  if (tid < 6) rd[tid] = 0.f;
  __syncthreads();
  float s[6] = {0,0,0,0,0,0};
  for (int d = tid; d < DIM; d += 256) {
    float gv = g[d], bv = bb[d];
    int h = (d >= HDIM);
    s[h]     += gv*gv;
    s[2 + h] += gv*bv;
    s[4 + h] += bv*bv;
  }
  for (int i = 0; i < 6; i++) atomicAdd(&rd[i], s[i]);
  __syncthreads();
  if (tid < 6) consts[tid] = rd[tid];
}

// ---------------- positional encoding (float64, matches numpy) -------------
__global__ __launch_bounds__(256) void pe_kernel(float* __restrict__ PE)
{
  int idx = blockIdx.x * 256 + threadIdx.x;
  if (idx >= 12 * DIM) return;
  int p = idx / DIM, d = idx - p * DIM;
  int j = d >> 1;
  double div = exp((double)(2 * j) * (-9.210340371976184 / 1152.0));
  double ang = (double)p * div;
  double v = (d & 1) ? cos(ang) : sin(ang);
  PE[idx] = (float)(v * 0.1);
}

// ---------------- Fb = bf16(input + PE) ------------------------------------
__global__ __launch_bounds__(256) void add_pe_bf(
    const float* __restrict__ sup, const float* __restrict__ qry,
    const float* __restrict__ PE, ushort* __restrict__ Fb)
{
  int idx = blockIdx.x * 256 + threadIdx.x;
  if (idx >= 900 * DIM) return;
  int row = idx / DIM, d = idx - row * DIM;
  int p = row % 12;
  float x = (row < 300) ? sup[idx] : qry[idx - 300 * DIM];
  Fb[idx] = f2bf(x + PE[p * DIM + d]);
}

// ---------------- W transpose+convert: Wt[n][k] bf16 -----------------------
__global__ __launch_bounds__(256) void conv_w(
    const float* __restrict__ kw, const float* __restrict__ vw,
    ushort* __restrict__ Wt)
{
  __shared__ float tileS[32][33];
  const int tid = threadIdx.x;
  const int kt = blockIdx.x * 32;    // K base
  const int ng0 = blockIdx.y * 32;   // N base (0..6880)
  const int b = ng0 / DIM, d0 = ng0 - b * DIM;
  const float* src = (b < 3) ? (kw + (size_t)b * DIM * DIM)
                             : (vw + (size_t)(b - 3) * DIM * DIM);
  const int r = tid >> 3, cs = (tid & 7) * 4;
  float4 vsrc = *(const float4*)(src + (size_t)(kt + r) * DIM + d0 + cs);
  tileS[r][cs+0] = vsrc.x; tileS[r][cs+1] = vsrc.y;
  tileS[r][cs+2] = vsrc.z; tileS[r][cs+3] = vsrc.w;
  __syncthreads();
  uint u0 = (uint)f2bf(tileS[cs+0][r]) | ((uint)f2bf(tileS[cs+1][r]) << 16);
  uint u1 = (uint)f2bf(tileS[cs+2][r]) | ((uint)f2bf(tileS[cs+3][r]) << 16);
  uint2 o; o.x = u0; o.y = u1;
  *(uint2*)(Wt + (size_t)(ng0 + r) * DIM + kt + cs) = o;
}

// ---------------- projection MFMA GEMM: C[900,6912] = Fb @ Wt^T ------------
__global__ __launch_bounds__(256) void gemm_proj_mfma(
    const ushort* __restrict__ Fb, const ushort* __restrict__ Wt,
    const float* __restrict__ kb, const float* __restrict__ vb,
    float* __restrict__ Ck, float* __restrict__ Cv)
{
  __shared__ __align__(16) ushort As[128][72];
  __shared__ __align__(16) ushort Bs[128][72];
  const int tid = threadIdx.x;
  const int col0 = blockIdx.x * 128;    // 0..6784
  const int row0 = blockIdx.y * 128;    // 0..896
  f32x4 acc[4][4] = {};
  const int wv = tid >> 6, lane = tid & 63;
  const int wm = wv >> 1, wn = wv & 1;
  for (int k0 = 0; k0 < DIM; k0 += 64) {
    __syncthreads();
    for (int sidx = tid; sidx < 1024; sidx += 256) {
      int rowa = sidx >> 3, kseg = sidx & 7;
      uint4 va = {0,0,0,0};
      int gm = row0 + rowa;
      if (gm < 900) va = *(const uint4*)(Fb + (size_t)gm * DIM + k0 + kseg * 8);
      *(uint4*)&As[rowa][kseg * 8] = va;
      int gc = col0 + rowa;
      uint4 vb4 = *(const uint4*)(Wt + (size_t)gc * DIM + k0 + kseg * 8);
      *(uint4*)&Bs[rowa][kseg * 8] = vb4;
    }
    __syncthreads();
    #pragma unroll
    for (int ks = 0; ks < 64; ks += 32) {
      short8 a[4], b[4];
      #pragma unroll
      for (int i = 0; i < 4; i++) {
        a[i] = *(const short8*)&As[wm*64 + i*16 + (lane & 15)][ks + (lane >> 4) * 8];
        b[i] = *(const short8*)&Bs[wn*64 + i*16 + (lane & 15)][ks + (lane >> 4) * 8];
      }
      #pragma unroll
      for (int mi = 0; mi < 4; mi++)
        #pragma unroll
        for (int ni = 0; ni < 4; ni++)
          acc[mi][ni] = __builtin_amdgcn_mfma_f32_16x16x32_bf16(a[mi], b[ni], acc[mi][ni], 0, 0, 0);
    }
  }
  const int b = col0 / DIM, d_base = col0 - b * DIM;
  #pragma unroll
  for (int mi = 0; mi < 4; mi++)
    #pragma unroll
    for (int ni = 0; ni < 4; ni++)
      #pragma unroll
      for (int r = 0; r < 4; r++) {
        int m = row0 + wm * 64 + mi * 16 + (lane >> 4) * 4 + r;
        if (m >= 900) continue;
        int n = wn * 64 + ni * 16 + (lane & 15);
        int d = d_base + n;
        float val = acc[mi][ni][r];
        if (b < 3) Ck[((size_t)m * 3 + b)       * DIM + d] = val + kb[d] * (1.f/3.f);
        else       Cv[((size_t)m * 3 + (b - 3)) * DIM + d] = val + vb[d] * (1.f/3.f);
      }
}

// ---------------- per frame-projection row stats (fp32) --------------------
__global__ __launch_bounds__(128) void row_stats(
    const float* __restrict__ Ck, const float* __restrict__ g,
    const float* __restrict__ bb, float* __restrict__ m_o,
    float* __restrict__ A_o, float* __restrict__ B_o)
{
  const int r = blockIdx.x, tid = threadIdx.x;
  const float* x = Ck + (size_t)r * DIM;
  float sm = 0, sa0 = 0, sa1 = 0, sb0 = 0, sb1 = 0;
  for (int d = tid; d < DIM; d += 128) {
    float xv = x[d], gv = g[d], bv = bb[d];
    float xg2 = xv * gv * gv, xgb = xv * gv * bv;
    if (d < HDIM) { sa0 += xg2; sb0 += xgb; } else { sa1 += xg2; sb1 += xgb; }
    sm += xv;
  }
  for (int o = 32; o > 0; o >>= 1) {
    sm  += __shfl_down(sm, o);  sa0 += __shfl_down(sa0, o); sa1 += __shfl_down(sa1, o);
    sb0 += __shfl_down(sb0, o); sb1 += __shfl_down(sb1, o);
  }
  __shared__ float red[2][5];
  if ((tid & 63) == 0) {
    int wv = tid >> 6;
    red[wv][0]=sm; red[wv][1]=sa0; red[wv][2]=sa1; red[wv][3]=sb0; red[wv][4]=sb1;
  }
  __syncthreads();
  if (tid == 0) {
    m_o[r]         = (red[0][0] + red[1][0]) * (1.f / 1152.f);
    A_o[r]         =  red[0][1] + red[1][1];
    A_o[2700 + r]  =  red[0][2] + red[1][2];
    B_o[r]         =  red[0][3] + red[1][3];
    B_o[2700 + r]  =  red[0][4] + red[1][4];
  }
}

// ---------------- per-sequence 36x36 self-Gram (fp32, full 1152) -----------
__global__ __launch_bounds__(256) void self_gram(
    const float* __restrict__ Ck, float* __restrict__ S)
{
  const int u = blockIdx.x, tid = threadIdx.x;
  __shared__ float CS[36][129];
  float acc[2][3] = {{0,0,0},{0,0,0}};
  const int ta = tid / 12, tb = tid - (tid / 12) * 12;
  for (int k0 = 0; k0 < DIM; k0 += 128) {
    __syncthreads();
    for (int idx = tid; idx < 36 * 128; idx += 256) {
      int rr = idx >> 7, kk = idx & 127;
      CS[rr][kk] = Ck[((size_t)u * 36 + rr) * DIM + k0 + kk];
    }
    __syncthreads();
    if (ta < 18) {
      for (int kk = 0; kk < 128; kk++) {
        float va0 = CS[ta*2][kk], va1 = CS[ta*2+1][kk];
        float vb0 = CS[tb*3][kk], vb1 = CS[tb*3+1][kk], vb2 = CS[tb*3+2][kk];
        acc[0][0]+=va0*vb0; acc[0][1]+=va0*vb1; acc[0][2]+=va0*vb2;
        acc[1][0]+=va1*vb0; acc[1][1]+=va1*vb1; acc[1][2]+=va1*vb2;
      }
    }
  }
  if (ta < 18) {
    #pragma unroll
    for (int i = 0; i < 2; i++)
      #pragma unroll
      for (int j = 0; j < 3; j++)
        S[u * 1296 + (ta*2+i) * 36 + tb*3+j] = acc[i][j];
  }
}

// ---------------- per-(seq,tuple) LN stats packed: kst[2][75][220] ---------
__global__ __launch_bounds__(256) void row_ln(
    const float* __restrict__ S, const float* __restrict__ m_i,
    const float* __restrict__ A_i, const float* __restrict__ B_i,
    const int* __restrict__ tup, float4* __restrict__ kst)
{
  const int u = blockIdx.x, tid = threadIdx.x;
  __shared__ float Ss[36][36];
  __shared__ float ms[36], As[2][36], Bs[2][36];
  for (int idx = tid; idx < 1296; idx += 256) (&Ss[0][0])[idx] = S[u * 1296 + idx];
  if (tid < 36) {
    ms[tid]    = m_i[u * 36 + tid];
    As[0][tid] = A_i[u * 36 + tid];  As[1][tid] = A_i[2700 + u * 36 + tid];
    Bs[0][tid] = B_i[u * 36 + tid];  Bs[1][tid] = B_i[2700 + u * 36 + tid];
  }
  __syncthreads();
  if (tid < NTUP) {
    int a0 = tup[tid*3+0]*3+0, a1 = tup[tid*3+1]*3+1, a2 = tup[tid*3+2]*3+2;
    float mu = ms[a0] + ms[a1] + ms[a2];
    float qq = Ss[a0][a0] + Ss[a1][a1] + Ss[a2][a2]
             + 2.f * (Ss[a0][a1] + Ss[a0][a2] + Ss[a1][a2]);
    float var = qq * (1.f / 1152.f) - mu * mu;
    float rr = rsqrtf(var + 1e-5f);
    kst[((size_t)0 * 75 + u) * 220 + tid] =
        make_float4(mu, rr, As[0][a0]+As[0][a1]+As[0][a2], Bs[0][a0]+Bs[0][a1]+Bs[0][a2]);
    kst[((size_t)1 * 75 + u) * 220 + tid] =
        make_float4(mu, rr, As[1][a0]+As[1][a1]+As[1][a2], Bs[1][a0]+Bs[1][a1]+Bs[1][a2]);
  }
}

// ---------------- Ckw = bf16(Ck * g) ---------------------------------------
__global__ __launch_bounds__(256) void conv_ckw(
    const float* __restrict__ Ck, const float* __restrict__ g,
    ushort* __restrict__ Ckw)
{
  size_t i = (size_t)blockIdx.x * 256 + threadIdx.x;
  if (i >= (size_t)2700 * DIM) return;
  int d = (int)(i % DIM);
  Ckw[i] = f2bf(Ck[i] * g[d]);
}

// ---------------- cross-Gram MFMA: Gb[h][1800][900] bf16 -------------------
__global__ __launch_bounds__(256) void cross_gram_mfma(
    const ushort* __restrict__ Ckw, ushort* __restrict__ Gb)
{
  __shared__ __align__(16) ushort As[128][72];
  __shared__ __align__(16) ushort Bs[128][72];
  const int tid = threadIdx.x;
  const int col0 = blockIdx.x * 128;   // N=900
  const int row0 = blockIdx.y * 128;   // M=1800
  const int h = blockIdx.z;
  f32x4 acc[4][4] = {};
  const int wv = tid >> 6, lane = tid & 63;
  const int wm = wv >> 1, wn = wv & 1;
  for (int k0 = 0; k0 < HDIM; k0 += 64) {
    __syncthreads();
    for (int sidx = tid; sidx < 1024; sidx += 256) {
      int rowa = sidx >> 3, kseg = sidx & 7;
      uint4 va = {0,0,0,0};
      int gm = row0 + rowa;
      if (gm < 1800)
        va = *(const uint4*)(Ckw + (size_t)(900 + gm) * DIM + h * HDIM + k0 + kseg * 8);
      *(uint4*)&As[rowa][kseg * 8] = va;
      uint4 vb = {0,0,0,0};
      int gn = col0 + rowa;
      if (gn < 900)
        vb = *(const uint4*)(Ckw + (size_t)gn * DIM + h * HDIM + k0 + kseg * 8);
      *(uint4*)&Bs[rowa][kseg * 8] = vb;
    }
    __syncthreads();
    #pragma unroll
    for (int ks = 0; ks < 64; ks += 32) {
      short8 a[4], b[4];
      #pragma unroll
      for (int i = 0; i < 4; i++) {
        a[i] = *(const short8*)&As[wm*64 + i*16 + (lane & 15)][ks + (lane >> 4) * 8];
        b[i] = *(const short8*)&Bs[wn*64 + i*16 + (lane & 15)][ks + (lane >> 4) * 8];
      }
      #pragma unroll
      for (int mi = 0; mi < 4; mi++)
        #pragma unroll
        for (int ni = 0; ni < 4; ni++)
          acc[mi][ni] = __builtin_amdgcn_mfma_f32_16x16x32_bf16(a[mi], b[ni], acc[mi][ni], 0, 0, 0);
    }
  }
  #pragma unroll
  for (int mi = 0; mi < 4; mi++)
    #pragma unroll
    for (int ni = 0; ni < 4; ni++)
      #pragma unroll
      for (int r = 0; r < 4; r++) {
        int m = row0 + wm * 64 + mi * 16 + (lane >> 4) * 4 + r;
        int n = col0 + wn * 64 + ni * 16 + (lane & 15);
        if (m < 1800 && n < 900)
          Gb[((size_t)h * 1800 + m) * 900 + n] = f2bf(acc[mi][ni][r]);
      }
}

// ---------------- fused MFMA attention ------------------------------------
// LDS budget: big 36096 + mid 22272 + M 5760 + red 256 + rq24S 64 + tupT 896
//           = 65344 B  (< 65536)
struct MidScore { ushort Eq[16][72]; ushort Gs[36][40]; };
union MidU { MidScore sc; ushort L[48][232]; };
union BigU { ushort P[16][1128]; ushort Kmat[224][72]; ushort Vt[18][580]; };

__global__ __launch_bounds__(256) void attn_kernel(
    const ushort* __restrict__ Gb, const float* __restrict__ Cv,
    const float4* __restrict__ kst, const uint* __restrict__ tupP,
    const float* __restrict__ consts, float* __restrict__ out)
{
  __shared__ __align__(16) BigU u;
  __shared__ __align__(16) MidU m_;
  __shared__ __align__(16) ushort Mlds[16][180];
  __shared__ float red[4][16];
  __shared__ float rq24S[16];
  __shared__ uint tupT[224];

  const int tid = threadIdx.x;
  const int chunk = blockIdx.x, w = blockIdx.y;
  const int qu = blockIdx.z >> 1, h = blockIdx.z & 1;
  const int tbase = chunk * CHUNK;
  const float Ggh = consts[h], Gbh = consts[2 + h], Bbh = consts[4 + h];
  const int wv = tid >> 6, lane = tid & 63;
  const int rowg = lane >> 4, col16 = lane & 15;

  // ---- init: zero Kmat + Eq, fill tupT ----
  for (int idx = tid; idx < 8064; idx += 256) ((uint*)u.Kmat)[idx] = 0;
  for (int idx = tid; idx < 576; idx += 256) ((uint*)m_.sc.Eq)[idx] = 0;
  if (tid < 224) tupT[tid] = (tid < 220) ? tupP[tid] : 0u;
  __syncthreads();
  if (tid < 4) u.Kmat[220 + tid][40] = f2bf(-1e30f);   // pad-col sentinel
  if (tid < CHUNK) {
    int t = tbase + tid;
    if (t < NTUP) {
      float4 q4 = kst[((size_t)h * 75 + 25 + qu) * 220 + t];
      uint tq = tupT[t];
      m_.sc.Eq[tid][(int)(tq & 255u) * 3 + 0] = f2bf(1.0f);
      m_.sc.Eq[tid][(int)((tq >> 8) & 255u) * 3 + 1] = f2bf(1.0f);
      m_.sc.Eq[tid][(int)((tq >> 16) & 255u) * 3 + 2] = f2bf(1.0f);
      m_.sc.Eq[tid][36] = f2bf(q4.z);                 // zgq
      m_.sc.Eq[tid][37] = f2bf(q4.x);                 // mq
      m_.sc.Eq[tid][38] = f2bf(q4.w - q4.x * Gbh);    // zbq - mq*Gbh
      rq24S[tid] = q4.y * (1.f / 24.f);
    } else rq24S[tid] = 0.f;
  }
  __syncthreads();

  short8 afr0 = *(const short8*)&m_.sc.Eq[col16][rowg * 8];
  short8 afr1 = *(const short8*)&m_.sc.Eq[col16][32 + rowg * 8];
  float rq24r[4];
  #pragma unroll
  for (int r = 0; r < 4; r++) rq24r[r] = rq24S[rowg * 4 + r];

  f32x4 acc[5][4];
  #pragma unroll
  for (int s = 0; s < 5; s++)
    #pragma unroll
    for (int i = 0; i < 4; i++) acc[s][i] = (f32x4){0.f, 0.f, 0.f, 0.f};

  // ---- score phase: per shot s, build Kmat then MFMA ----
  #pragma unroll
  for (int s = 0; s < 5; s++) {
    __syncthreads();
    // stage Gs[36][36] (bf16) from Gb
    for (int idx = tid; idx < 648; idx += 256) {
      int row = idx / 18, part = idx - row * 18;
      ((uint*)&m_.sc.Gs[row][0])[part] =
        *(const uint*)(Gb + ((size_t)(h * 1800 + qu * 36 + row)) * 900
                          + (w * 5 + s) * 36 + part * 2);
    }
    __syncthreads();
    if (tid < NTUP) {
      int t2 = tid;
      uint tk = tupT[t2];
      int b0 = (int)(tk & 255u) * 3, b1 = (int)((tk >> 8) & 255u) * 3 + 1,
          b2 = (int)((tk >> 16) & 255u) * 3 + 2;
      float4 k4 = kst[((size_t)h * 75 + w * 5 + s) * 220 + t2];
      float mk = k4.x, rk = k4.y, zgk = k4.z, zbk = k4.w;
      #pragma unroll 6
      for (int a = 0; a < 36; a++) {
        float v = bf2f(m_.sc.Gs[a][b0]) + bf2f(m_.sc.Gs[a][b1]) + bf2f(m_.sc.Gs[a][b2]);
        u.Kmat[t2][a] = f2bf(rk * v);
      }
      u.Kmat[t2][36] = f2bf(-rk * mk);
      u.Kmat[t2][37] = f2bf(rk * (mk * Ggh - zgk));
      u.Kmat[t2][38] = f2bf(1.0f);
      u.Kmat[t2][40] = f2bf((rk * zbk - rk * mk * Gbh + Bbh) * (1.f / 24.f));
    }
    __syncthreads();
    #pragma unroll
    for (int i = 0; i < 4; i++) {
      int ntile = wv + 4 * i;
      if (ntile < 14) {
        short8 bf0 = *(const short8*)&u.Kmat[ntile * 16 + col16][rowg * 8];
        short8 bf1 = *(const short8*)&u.Kmat[ntile * 16 + col16][32 + rowg * 8];
        f32x4 a4 = acc[s][i];
        a4 = __builtin_amdgcn_mfma_f32_16x16x32_bf16(afr0, bf0, a4, 0, 0, 0);
        a4 = __builtin_amdgcn_mfma_f32_16x16x32_bf16(afr1, bf1, a4, 0, 0, 0);
        float vc = bf2f(u.Kmat[ntile * 16 + col16][40]);
        #pragma unroll
        for (int r = 0; r < 4; r++) a4[r] = rq24r[r] * a4[r] + vc;
        acc[s][i] = a4;
      }
    }
  }

  // ---- softmax over all 1100 cols (rows = q-tuples) ----
  float mxr[4] = {-1e30f, -1e30f, -1e30f, -1e30f};
  #pragma unroll
  for (int s = 0; s < 5; s++)
    #pragma unroll
    for (int i = 0; i < 4; i++)
      if (wv + 4 * i < 14) {
        #pragma unroll
        for (int r = 0; r < 4; r++) mxr[r] = fmaxf(mxr[r], acc[s][i][r]);
      }
  #pragma unroll
  for (int o = 8; o > 0; o >>= 1) {
    #pragma unroll
    for (int r = 0; r < 4; r++) mxr[r] = fmaxf(mxr[r], __shfl_xor(mxr[r], o));
  }
  if (col16 == 0) {
    #pragma unroll
    for (int r = 0; r < 4; r++) red[wv][rowg * 4 + r] = mxr[r];
  }
  __syncthreads();
  float mxg[4];
  #pragma unroll
  for (int r = 0; r < 4; r++) {
    int row = rowg * 4 + r;
    mxg[r] = fmaxf(fmaxf(red[0][row], red[1][row]), fmaxf(red[2][row], red[3][row]));
  }
  __syncthreads();
  float smr[4] = {0.f, 0.f, 0.f, 0.f};
  #pragma unroll
  for (int s = 0; s < 5; s++)
    #pragma unroll
    for (int i = 0; i < 4; i++) {
      int ntile = wv + 4 * i;
      if (ntile < 14) {
        #pragma unroll
        for (int r = 0; r < 4; r++) {
          float p = __expf(acc[s][i][r] - mxg[r]);
          smr[r] += p;
          u.P[rowg * 4 + r][s * 224 + ntile * 16 + col16] = f2bf(p);
        }
      }
    }
  #pragma unroll
  for (int o = 8; o > 0; o >>= 1) {
    #pragma unroll
    for (int r = 0; r < 4; r++) smr[r] += __shfl_xor(smr[r], o);
  }
  if (col16 == 0) {
    #pragma unroll
    for (int r = 0; r < 4; r++) red[wv][rowg * 4 + r] = smr[r];
  }
  __syncthreads();
  float inv4[4];
  #pragma unroll
  for (int r = 0; r < 4; r++) {
    int row = rowg * 4 + r;
    inv4[r] = 1.0f / (red[0][row] + red[1][row] + red[2][row] + red[3][row]);
  }

  // ---- build L (overwrites Eq/Gs) ----
  for (int idx = tid; idx < 5568; idx += 256) ((uint*)m_.L)[idx] = 0;
  __syncthreads();
  if (tid < NTUP) {
    uint tk = tupT[tid];
    m_.L[0 * 12 + (int)(tk & 255u)][tid]        = f2bf(1.0f);
    m_.L[1 * 12 + (int)((tk >> 8) & 255u)][tid] = f2bf(1.0f);
    m_.L[2 * 12 + (int)((tk >> 16) & 255u)][tid]= f2bf(1.0f);
  }
  __syncthreads();

  // ---- marginal MFMA: M[16][s*36+bin] = P[16][s-slice] . L ----
  #pragma unroll
  for (int u2 = 0; u2 < 4; u2++) {
    int unit = wv + 4 * u2;
    if (unit < 15) {
      int s = unit / 3, ntl = unit - s * 3;
      f32x4 macc = {0.f, 0.f, 0.f, 0.f};
      #pragma unroll
      for (int ks = 0; ks < 7; ks++) {
        short8 pf = *(const short8*)&u.P[col16][s * 224 + ks * 32 + rowg * 8];
        short8 lf = *(const short8*)&m_.L[ntl * 16 + col16][ks * 32 + rowg * 8];
        macc = __builtin_amdgcn_mfma_f32_16x16x32_bf16(pf, lf, macc, 0, 0, 0);
      }
      int col = ntl * 16 + col16;
      if (col < 36) {
        #pragma unroll
        for (int r = 0; r < 4; r++)
          Mlds[rowg * 4 + r][s * 36 + col] = f2bf(macc[r] * inv4[r]);
      }
    }
  }
  __syncthreads();

  // ---- PV: proto = M @ V_h (bf16), fused squared-distance vs q_vs --------
  float acc2[2][18];
  #pragma unroll
  for (int i = 0; i < 2; i++)
    #pragma unroll
    for (int e = 0; e < 18; e++) acc2[i][e] = 0.f;
  const int ty = tid >> 5, tx = tid & 31;
  const int tq0 = ty * 2, dd0 = tx * 18;
  for (int c = 0; c < 10; c++) {
    __syncthreads();
    for (int idx = tid; idx < 18 * 576; idx += 256) {
      int kk = idx / 576, dd = idx - kk * 576;
      int kg = c * 18 + kk;
      int s = kg / 36, rem = kg - s * 36, j = rem / 12, p = rem - j * 12;
      u.Vt[kk][dd] = f2bf(Cv[((size_t)((w * 5 + s) * 36 + p * 3 + j)) * DIM + h * HDIM + dd]);
    }
    __syncthreads();
    for (int kk = 0; kk < 18; kk++) {
      int kg = c * 18 + kk;
      float mv0 = bf2f(Mlds[tq0 + 0][kg]), mv1 = bf2f(Mlds[tq0 + 1][kg]);
      #pragma unroll
      for (int e = 0; e < 18; e++) {
        float vv = bf2f(u.Vt[kk][dd0 + e]);
        acc2[0][e] += mv0 * vv; acc2[1][e] += mv1 * vv;
      }
    }
  }

  float sq = 0.f;
  #pragma unroll
  for (int i = 0; i < 2; i++) {
    int t = tbase + tq0 + i;
    if (t < NTUP) {
      uint tq = tupP[t];
      int f0 = (int)(tq & 255u), f1 = (int)((tq >> 8) & 255u), f2v = (int)((tq >> 16) & 255u);
      const float* c0 = &Cv[((size_t)((25 + qu) * 36 + f0 * 3 + 0)) * DIM + h * HDIM + dd0];
      const float* c1p = &Cv[((size_t)((25 + qu) * 36 + f1 * 3 + 1)) * DIM + h * HDIM + dd0];
      const float* c2 = &Cv[((size_t)((25 + qu) * 36 + f2v * 3 + 2)) * DIM + h * HDIM + dd0];
      #pragma unroll
      for (int e = 0; e < 18; e++) {
        float qv = c0[e] + c1p[e] + c2[e];
        float d = qv - acc2[i][e];
        sq += d * d;
      }
    }
  }
  #pragma unroll
  for (int o = 32; o > 0; o >>= 1) sq += __shfl_down(sq, o);
  __syncthreads();
  if ((tid & 63) == 0) red[0][tid >> 6] = sq;
  __syncthreads();
  if (tid == 0) {
    float tot = red[0][0] + red[0][1] + red[0][2] + red[0][3];
    atomicAdd(&out[qu * 5 + w], -tot * (1.0f / 220.0f));
  }
}

// ---------------------------------------------------------------------------
extern "C" void kernel_launch(void* const* d_in, const int* in_sizes, int n_in,
                              void* d_out, int out_size, void* d_ws, size_t ws_size,
                              hipStream_t stream) {
  const float* support = (const float*)d_in[0];
  const float* queries = (const float*)d_in[1];
  // d_in[2] = support_labels (sorted by construction; unused)
  const float* kw = (const float*)d_in[3];
  const float* kb = (const float*)d_in[4];
  const float* vw = (const float*)d_in[5];
  const float* vb = (const float*)d_in[6];
  const float* g  = (const float*)d_in[7];
  const float* bb = (const float*)d_in[8];
  float* out = (float*)d_out;

  float* ws = (float*)d_ws;
  size_t off = 0;
  auto alloc = [&](size_t n) { float* p = ws + off; off += (n + 63) & ~(size_t)63; return p; };
  float* PE     = alloc(12 * DIM);
  // Union A: Fb (bf16 900x1152) then Ckw (bf16 2700x1152)
  float* uA     = alloc(1555200);
  ushort* Fb    = (ushort*)uA;
  ushort* Ckw   = (ushort*)uA;
  // Union B: Wt (bf16 6912x1152) then Gb (bf16 2x1800x900)
  float* uB     = alloc(3981312);
  ushort* Wt    = (ushort*)uB;
  ushort* Gb    = (ushort*)uB;
  float* Ck     = alloc((size_t)2700 * DIM);
  float* Cv     = alloc((size_t)2700 * DIM);
  float* m_arr  = alloc(2700);
  float* A_arr  = alloc(2 * 2700);
  float* B_arr  = alloc(2 * 2700);
  float* S      = alloc(75 * 1296);
  float4* kst   = (float4*)alloc(2 * 75 * 220 * 4);
  float* consts = alloc(64);
  int* tup   = (int*)alloc(660);
  uint* tupP = (uint*)alloc(256);

  hipMemsetAsync(d_out, 0, (size_t)out_size * sizeof(float), stream);

  init_tables<<<1, 256, 0, stream>>>(g, bb, tup, tupP, consts);
  pe_kernel<<<(12 * DIM + 255) / 256, 256, 0, stream>>>(PE);
  add_pe_bf<<<(900 * DIM + 255) / 256, 256, 0, stream>>>(support, queries, PE, Fb);
  conv_w<<<dim3(36, 216), 256, 0, stream>>>(kw, vw, Wt);
  gemm_proj_mfma<<<dim3(54, 8), 256, 0, stream>>>(Fb, Wt, kb, vb, Ck, Cv);
  row_stats<<<2700, 128, 0, stream>>>(Ck, g, bb, m_arr, A_arr, B_arr);
  self_gram<<<75, 256, 0, stream>>>(Ck, S);
  row_ln<<<75, 256, 0, stream>>>(S, m_arr, A_arr, B_arr, tup, kst);
  conv_ckw<<<(int)(((size_t)2700 * DIM + 255) / 256), 256, 0, stream>>>(Ck, g, Ckw);
  cross_gram_mfma<<<dim3(8, 15, 2), 256, 0, stream>>>(Ckw, Gb);
  attn_kernel<<<dim3(14, 5, 100), 256, 0, stream>>>(Gb, Cv, kst, tupP, consts, out);
}

// Round 5
// 930.497 us; speedup vs baseline: 2.8527x; 2.8527x over previous
//
#include <hip/hip_runtime.h>
#include <math.h>

// ---------------------------------------------------------------------------
// MultiTemporalCrossTransformer — factorized algorithm, round 5.
//   * projections via bf16 MFMA GEMM (frame-factorized: 900x6912x1152)
//   * LN stats from per-frame means + fp32 self-Gram
//   * scores: (Eq.Gs).Ek^T associativity -> Qg gather + MFMA vs static 0/1 Ek
//     (Ek/L fragments synthesized arithmetically in registers; stats fp32 post)
//   * marginalization via per-shot MFMA P_s . L^T -> M written to global bf16
//   * PV + distance as a separate batched 128x128x192 MFMA GEMM kernel
// ---------------------------------------------------------------------------

#define DIM 1152
#define HDIM 576
#define NTUP 220

typedef __attribute__((ext_vector_type(4))) float f32x4;
typedef __attribute__((ext_vector_type(8))) short short8;

__device__ __forceinline__ ushort f2bf(float x) {
  union { float f; unsigned u; } v; v.f = x;
  unsigned r = (v.u + 0x7FFFu + ((v.u >> 16) & 1u)) >> 16;
  return (ushort)r;
}
__device__ __forceinline__ float bf2f(ushort x) {
  union { unsigned u; float f; } v; v.u = ((unsigned)x) << 16;
  return v.f;
}

// ---------------- init: tuple tables, g/b constants ------------------------
__global__ __launch_bounds__(256) void init_tables(
    const float* __restrict__ g, const float* __restrict__ bb,
    int* __restrict__ tup, uint* __restrict__ tupP, float* __restrict__ consts)
{
  const int tid = threadIdx.x;
  if (tid < 220) {
    int t = tid, idx = 0;
    for (int a = 0; a < 10; a++)
      for (int b2 = a + 1; b2 < 11; b2++)
        for (int c = b2 + 1; c < 12; c++) {
          if (idx == t) {
            tup[t*3+0]=a; tup[t*3+1]=b2; tup[t*3+2]=c;
            tupP[t] = (uint)a | ((uint)b2 << 8) | ((uint)c << 16);
          }
          idx++;
        }
  }
  __shared__ float rd[6];
  if (tid < 6) rd[tid] = 0.f;
  __syncthreads();
  float s[6] = {0,0,0,0,0,0};
  for (int d = tid; d < DIM; d += 256) {
    float gv = g[d], bv = bb[d];
    int h = (d >= HDIM);
    s[h]     += gv*gv;
    s[2 + h] += gv*bv;
    s[4 + h] += bv*bv;
  }
  for (int i = 0; i < 6; i++) atomicAdd(&rd[i], s[i]);
  __syncthreads();
  if (tid < 6) consts[tid] = rd[tid];
}

// ---------------- positional encoding (float64, matches numpy) -------------
__global__ __launch_bounds__(256) void pe_kernel(float* __restrict__ PE)
{
  int idx = blockIdx.x * 256 + threadIdx.x;
  if (idx >= 12 * DIM) return;
  int p = idx / DIM, d = idx - p * DIM;
  int j = d >> 1;
  double div = exp((double)(2 * j) * (-9.210340371976184 / 1152.0));
  double ang = (double)p * div;
  double v = (d & 1) ? cos(ang) : sin(ang);
  PE[idx] = (float)(v * 0.1);
}

// ---------------- Fb = bf16(input + PE) ------------------------------------
__global__ __launch_bounds__(256) void add_pe_bf(
    const float* __restrict__ sup, const float* __restrict__ qry,
    const float* __restrict__ PE, ushort* __restrict__ Fb)
{
  int idx = blockIdx.x * 256 + threadIdx.x;
  if (idx >= 900 * DIM) return;
  int row = idx / DIM, d = idx - row * DIM;
  int p = row % 12;
  float x = (row < 300) ? sup[idx] : qry[idx - 300 * DIM];
  Fb[idx] = f2bf(x + PE[p * DIM + d]);
}

// ---------------- W transpose+convert: Wt[n][k] bf16 -----------------------
__global__ __launch_bounds__(256) void conv_w(
    const float* __restrict__ kw, const float* __restrict__ vw,
    ushort* __restrict__ Wt)
{
  __shared__ float tileS[32][33];
  const int tid = threadIdx.x;
  const int kt = blockIdx.x * 32;    // K base
  const int ng0 = blockIdx.y * 32;   // N base (0..6880)
  const int b = ng0 / DIM, d0 = ng0 - b * DIM;
  const float* src = (b < 3) ? (kw + (size_t)b * DIM * DIM)
                             : (vw + (size_t)(b - 3) * DIM * DIM);
  const int r = tid >> 3, cs = (tid & 7) * 4;
  float4 vsrc = *(const float4*)(src + (size_t)(kt + r) * DIM + d0 + cs);
  tileS[r][cs+0] = vsrc.x; tileS[r][cs+1] = vsrc.y;
  tileS[r][cs+2] = vsrc.z; tileS[r][cs+3] = vsrc.w;
  __syncthreads();
  uint u0 = (uint)f2bf(tileS[cs+0][r]) | ((uint)f2bf(tileS[cs+1][r]) << 16);
  uint u1 = (uint)f2bf(tileS[cs+2][r]) | ((uint)f2bf(tileS[cs+3][r]) << 16);
  uint2 o; o.x = u0; o.y = u1;
  *(uint2*)(Wt + (size_t)(ng0 + r) * DIM + kt + cs) = o;
}

// ---------------- projection MFMA GEMM: C[900,6912] = Fb @ Wt^T ------------
__global__ __launch_bounds__(256) void gemm_proj_mfma(
    const ushort* __restrict__ Fb, const ushort* __restrict__ Wt,
    const float* __restrict__ kb, const float* __restrict__ vb,
    float* __restrict__ Ck, float* __restrict__ Cv)
{
  __shared__ __align__(16) ushort As[128][72];
  __shared__ __align__(16) ushort Bs[128][72];
  const int tid = threadIdx.x;
  const int col0 = blockIdx.x * 128;    // 0..6784
  const int row0 = blockIdx.y * 128;    // 0..896
  f32x4 acc[4][4] = {};
  const int wv = tid >> 6, lane = tid & 63;
  const int wm = wv >> 1, wn = wv & 1;
  for (int k0 = 0; k0 < DIM; k0 += 64) {
    __syncthreads();
    for (int sidx = tid; sidx < 1024; sidx += 256) {
      int rowa = sidx >> 3, kseg = sidx & 7;
      uint4 va = {0,0,0,0};
      int gm = row0 + rowa;
      if (gm < 900) va = *(const uint4*)(Fb + (size_t)gm * DIM + k0 + kseg * 8);
      *(uint4*)&As[rowa][kseg * 8] = va;
      int gc = col0 + rowa;
      uint4 vb4 = *(const uint4*)(Wt + (size_t)gc * DIM + k0 + kseg * 8);
      *(uint4*)&Bs[rowa][kseg * 8] = vb4;
    }
    __syncthreads();
    #pragma unroll
    for (int ks = 0; ks < 64; ks += 32) {
      short8 a[4], b[4];
      #pragma unroll
      for (int i = 0; i < 4; i++) {
        a[i] = *(const short8*)&As[wm*64 + i*16 + (lane & 15)][ks + (lane >> 4) * 8];
        b[i] = *(const short8*)&Bs[wn*64 + i*16 + (lane & 15)][ks + (lane >> 4) * 8];
      }
      #pragma unroll
      for (int mi = 0; mi < 4; mi++)
        #pragma unroll
        for (int ni = 0; ni < 4; ni++)
          acc[mi][ni] = __builtin_amdgcn_mfma_f32_16x16x32_bf16(a[mi], b[ni], acc[mi][ni], 0, 0, 0);
    }
  }
  const int b = col0 / DIM, d_base = col0 - b * DIM;
  #pragma unroll
  for (int mi = 0; mi < 4; mi++)
    #pragma unroll
    for (int ni = 0; ni < 4; ni++)
      #pragma unroll
      for (int r = 0; r < 4; r++) {
        int m = row0 + wm * 64 + mi * 16 + (lane >> 4) * 4 + r;
        if (m >= 900) continue;
        int n = wn * 64 + ni * 16 + (lane & 15);
        int d = d_base + n;
        float val = acc[mi][ni][r];
        if (b < 3) Ck[((size_t)m * 3 + b)       * DIM + d] = val + kb[d] * (1.f/3.f);
        else       Cv[((size_t)m * 3 + (b - 3)) * DIM + d] = val + vb[d] * (1.f/3.f);
      }
}

// ---------------- per frame-projection row stats (fp32) --------------------
__global__ __launch_bounds__(128) void row_stats(
    const float* __restrict__ Ck, const float* __restrict__ g,
    const float* __restrict__ bb, float* __restrict__ m_o,
    float* __restrict__ A_o, float* __restrict__ B_o)
{
  const int r = blockIdx.x, tid = threadIdx.x;
  const float* x = Ck + (size_t)r * DIM;
  float sm = 0, sa0 = 0, sa1 = 0, sb0 = 0, sb1 = 0;
  for (int d = tid; d < DIM; d += 128) {
    float xv = x[d], gv = g[d], bv = bb[d];
    float xg2 = xv * gv * gv, xgb = xv * gv * bv;
    if (d < HDIM) { sa0 += xg2; sb0 += xgb; } else { sa1 += xg2; sb1 += xgb; }
    sm += xv;
  }
  for (int o = 32; o > 0; o >>= 1) {
    sm  += __shfl_down(sm, o);  sa0 += __shfl_down(sa0, o); sa1 += __shfl_down(sa1, o);
    sb0 += __shfl_down(sb0, o); sb1 += __shfl_down(sb1, o);
  }
  __shared__ float red[2][5];
  if ((tid & 63) == 0) {
    int wv = tid >> 6;
    red[wv][0]=sm; red[wv][1]=sa0; red[wv][2]=sa1; red[wv][3]=sb0; red[wv][4]=sb1;
  }
  __syncthreads();
  if (tid == 0) {
    m_o[r]         = (red[0][0] + red[1][0]) * (1.f / 1152.f);
    A_o[r]         =  red[0][1] + red[1][1];
    A_o[2700 + r]  =  red[0][2] + red[1][2];
    B_o[r]         =  red[0][3] + red[1][3];
    B_o[2700 + r]  =  red[0][4] + red[1][4];
  }
}

// ---------------- per-sequence 36x36 self-Gram (fp32, full 1152) -----------
__global__ __launch_bounds__(256) void self_gram(
    const float* __restrict__ Ck, float* __restrict__ S)
{
  const int u = blockIdx.x, tid = threadIdx.x;
  __shared__ float CS[36][129];
  float acc[2][3] = {{0,0,0},{0,0,0}};
  const int ta = tid / 12, tb = tid - (tid / 12) * 12;
  for (int k0 = 0; k0 < DIM; k0 += 128) {
    __syncthreads();
    for (int idx = tid; idx < 36 * 128; idx += 256) {
      int rr = idx >> 7, kk = idx & 127;
      CS[rr][kk] = Ck[((size_t)u * 36 + rr) * DIM + k0 + kk];
    }
    __syncthreads();
    if (ta < 18) {
      for (int kk = 0; kk < 128; kk++) {
        float va0 = CS[ta*2][kk], va1 = CS[ta*2+1][kk];
        float vb0 = CS[tb*3][kk], vb1 = CS[tb*3+1][kk], vb2 = CS[tb*3+2][kk];
        acc[0][0]+=va0*vb0; acc[0][1]+=va0*vb1; acc[0][2]+=va0*vb2;
        acc[1][0]+=va1*vb0; acc[1][1]+=va1*vb1; acc[1][2]+=va1*vb2;
      }
    }
  }
  if (ta < 18) {
    #pragma unroll
    for (int i = 0; i < 2; i++)
      #pragma unroll
      for (int j = 0; j < 3; j++)
        S[u * 1296 + (ta*2+i) * 36 + tb*3+j] = acc[i][j];
  }
}

// ---------------- per-(seq,tuple) LN stats packed: kst[2][75][220] ---------
__global__ __launch_bounds__(256) void row_ln(
    const float* __restrict__ S, const float* __restrict__ m_i,
    const float* __restrict__ A_i, const float* __restrict__ B_i,
    const int* __restrict__ tup, float4* __restrict__ kst)
{
  const int u = blockIdx.x, tid = threadIdx.x;
  __shared__ float Ss[36][36];
  __shared__ float ms[36], As[2][36], Bs[2][36];
  for (int idx = tid; idx < 1296; idx += 256) (&Ss[0][0])[idx] = S[u * 1296 + idx];
  if (tid < 36) {
    ms[tid]    = m_i[u * 36 + tid];
    As[0][tid] = A_i[u * 36 + tid];  As[1][tid] = A_i[2700 + u * 36 + tid];
    Bs[0][tid] = B_i[u * 36 + tid];  Bs[1][tid] = B_i[2700 + u * 36 + tid];
  }
  __syncthreads();
  if (tid < NTUP) {
    int a0 = tup[tid*3+0]*3+0, a1 = tup[tid*3+1]*3+1, a2 = tup[tid*3+2]*3+2;
    float mu = ms[a0] + ms[a1] + ms[a2];
    float qq = Ss[a0][a0] + Ss[a1][a1] + Ss[a2][a2]
             + 2.f * (Ss[a0][a1] + Ss[a0][a2] + Ss[a1][a2]);
    float var = qq * (1.f / 1152.f) - mu * mu;
    float rr = rsqrtf(var + 1e-5f);
    kst[((size_t)0 * 75 + u) * 220 + tid] =
        make_float4(mu, rr, As[0][a0]+As[0][a1]+As[0][a2], Bs[0][a0]+Bs[0][a1]+Bs[0][a2]);
    kst[((size_t)1 * 75 + u) * 220 + tid] =
        make_float4(mu, rr, As[1][a0]+As[1][a1]+As[1][a2], Bs[1][a0]+Bs[1][a1]+Bs[1][a2]);
  }
}

// ---------------- Ckw = bf16(Ck * g) ---------------------------------------
__global__ __launch_bounds__(256) void conv_ckw(
    const float* __restrict__ Ck, const float* __restrict__ g,
    ushort* __restrict__ Ckw)
{
  size_t i = (size_t)blockIdx.x * 256 + threadIdx.x;
  if (i >= (size_t)2700 * DIM) return;
  int d = (int)(i % DIM);
  Ckw[i] = f2bf(Ck[i] * g[d]);
}

// ---------------- cross-Gram MFMA: Gb[h][1800][900] bf16 -------------------
__global__ __launch_bounds__(256) void cross_gram_mfma(
    const ushort* __restrict__ Ckw, ushort* __restrict__ Gb)
{
  __shared__ __align__(16) ushort As[128][72];
  __shared__ __align__(16) ushort Bs[128][72];
  const int tid = threadIdx.x;
  const int col0 = blockIdx.x * 128;   // N=900
  const int row0 = blockIdx.y * 128;   // M=1800
  const int h = blockIdx.z;
  f32x4 acc[4][4] = {};
  const int wv = tid >> 6, lane = tid & 63;
  const int wm = wv >> 1, wn = wv & 1;
  for (int k0 = 0; k0 < HDIM; k0 += 64) {
    __syncthreads();
    for (int sidx = tid; sidx < 1024; sidx += 256) {
      int rowa = sidx >> 3, kseg = sidx & 7;
      uint4 va = {0,0,0,0};
      int gm = row0 + rowa;
      if (gm < 1800)
        va = *(const uint4*)(Ckw + (size_t)(900 + gm) * DIM + h * HDIM + k0 + kseg * 8);
      *(uint4*)&As[rowa][kseg * 8] = va;
      uint4 vb = {0,0,0,0};
      int gn = col0 + rowa;
      if (gn < 900)
        vb = *(const uint4*)(Ckw + (size_t)gn * DIM + h * HDIM + k0 + kseg * 8);
      *(uint4*)&Bs[rowa][kseg * 8] = vb;
    }
    __syncthreads();
    #pragma unroll
    for (int ks = 0; ks < 64; ks += 32) {
      short8 a[4], b[4];
      #pragma unroll
      for (int i = 0; i < 4; i++) {
        a[i] = *(const short8*)&As[wm*64 + i*16 + (lane & 15)][ks + (lane >> 4) * 8];
        b[i] = *(const short8*)&Bs[wn*64 + i*16 + (lane & 15)][ks + (lane >> 4) * 8];
      }
      #pragma unroll
      for (int mi = 0; mi < 4; mi++)
        #pragma unroll
        for (int ni = 0; ni < 4; ni++)
          acc[mi][ni] = __builtin_amdgcn_mfma_f32_16x16x32_bf16(a[mi], b[ni], acc[mi][ni], 0, 0, 0);
    }
  }
  #pragma unroll
  for (int mi = 0; mi < 4; mi++)
    #pragma unroll
    for (int ni = 0; ni < 4; ni++)
      #pragma unroll
      for (int r = 0; r < 4; r++) {
        int m = row0 + wm * 64 + mi * 16 + (lane >> 4) * 4 + r;
        int n = col0 + wn * 64 + ni * 16 + (lane & 15);
        if (m < 1800 && n < 900)
          Gb[((size_t)h * 1800 + m) * 900 + n] = f2bf(acc[mi][ni][r]);
      }
}

// ---------------- Vt[w*2+h][d=576][k=192] bf16 (transposed V, K-padded) ----
__global__ __launch_bounds__(256) void vt_build(
    const float* __restrict__ Cv, ushort* __restrict__ Vt)
{
  __shared__ ushort T[192][72];
  const int tid = threadIdx.x;
  const int nb = blockIdx.x, z = blockIdx.y;
  const int w = z >> 1, h = z & 1;
  const int n0 = nb * 64;
  for (int idx = tid; idx < 12288; idx += 256) {
    int bin = idx >> 6, nc = idx & 63;
    ushort v = 0;
    if (bin < 180) {
      int s = bin / 36, rem = bin - s * 36, j = rem / 12, p = rem - j * 12;
      v = f2bf(Cv[(size_t)((w*5+s)*36 + p*3 + j) * DIM + h * HDIM + n0 + nc]);
    }
    T[bin][nc] = v;
  }
  __syncthreads();
  for (int u4i = tid; u4i < 1536; u4i += 256) {
    int n = u4i / 24, kc = (u4i - n * 24) * 8;
    ushort tmp[8];
    #pragma unroll
    for (int e = 0; e < 8; e++) tmp[e] = T[kc + e][n];
    *(uint4*)(Vt + ((size_t)z * 576 + n0 + n) * 192 + kc) = *(uint4*)tmp;
  }
}

// ---------------- attn2: scores + softmax + marginal -> Mg -----------------
// LDS: GsS 12960 + kstS 17920 + U 14336 + qstS 1792 + tupT 896 + red 256
//    ~= 48.2 KB  -> 3 blocks/CU
__global__ __launch_bounds__(256) void attn2(
    const ushort* __restrict__ Gb, const float4* __restrict__ kst,
    const uint* __restrict__ tupP, const float* __restrict__ consts,
    ushort* __restrict__ Mg)
{
  __shared__ __align__(16) ushort GsS[5][36][36];
  __shared__ __align__(16) float4 kstS[5][224];
  __shared__ __align__(16) union UU { ushort Qg[5][16][64]; ushort Ps[2][16][224]; } U;
  __shared__ __align__(16) float4 qstS[112];
  __shared__ uint tupT[224];
  __shared__ float red[4][16];

  const int tid = threadIdx.x;
  const int half = blockIdx.x, w = blockIdx.y;
  const int qu = blockIdx.z >> 1, h = blockIdx.z & 1;
  const float Ggh = consts[h], Gbh = consts[2 + h], Bbh = consts[4 + h];
  const int wv = tid >> 6, lane = tid & 63;
  const int rowg = lane >> 4, col16 = lane & 15;

  for (int idx = tid; idx < 224; idx += 256) tupT[idx] = (idx < 220) ? tupP[idx] : 0u;
  for (int idx = tid; idx < 3240; idx += 256) {
    int s = idx / 648, rem = idx - s * 648, a = rem / 18, bp = rem - a * 18;
    ((uint*)&GsS[s][a][0])[bp] =
      *(const uint*)(Gb + (size_t)(h*1800 + qu*36 + a) * 900 + (w*5+s)*36 + bp*2);
  }
  for (int idx = tid; idx < 1120; idx += 256) {
    int s = idx / 224, k = idx - s * 224;
    float4 v;
    if (k < 220) {
      float4 t4 = kst[((size_t)h*75 + w*5 + s) * 220 + k];
      v = make_float4(t4.x, t4.y, t4.z, (t4.y*(t4.w - t4.x*Gbh) + Bbh) * (1.f/24.f));
    } else v = make_float4(0.f, 0.f, 0.f, -1e30f);
    kstS[s][k] = v;
  }
  for (int idx = tid; idx < 112; idx += 256) {
    int t = half * 112 + idx;
    float4 v = make_float4(0.f, 0.f, 0.f, 0.f);
    if (t < 220) {
      float4 q4 = kst[((size_t)h*75 + 25 + qu) * 220 + t];
      v = make_float4(q4.x, q4.y * (1.f/24.f), q4.z,
                      q4.y * (q4.w - q4.x*Gbh) * (1.f/24.f));
    }
    qstS[idx] = v;
  }
  __syncthreads();

  // static Ek B-fragments (score MFMA), synthesized in registers
  short8 ebf[4][2];
  #pragma unroll
  for (int i = 0; i < 4; i++) {
    int ntile = wv + 4*i;
    uint tk = tupT[ntile*16 + col16];
    int b0 = (int)(tk & 255u)*3, b1 = (int)((tk>>8)&255u)*3+1, b2 = (int)((tk>>16)&255u)*3+2;
    #pragma unroll
    for (int ks = 0; ks < 2; ks++)
      #pragma unroll
      for (int e = 0; e < 8; e++) {
        int colb = ks*32 + rowg*8 + e;
        ebf[i][ks][e] = (short)((colb==b0 || colb==b1 || colb==b2) ? 0x3F80 : 0);
      }
  }
  // static L^T B-fragments (marginal MFMA), waves 0..2 own bin-tile = wv
  short8 lbf[7];
  {
    int bin = wv*16 + col16;
    int j = bin / 12, p = bin - j*12;
    #pragma unroll
    for (int ks = 0; ks < 7; ks++)
      #pragma unroll
      for (int e = 0; e < 8; e++) {
        int k = ks*32 + rowg*8 + e;
        uint tk = tupT[k];
        int f = (j==0) ? (int)(tk & 255u) : (j==1) ? (int)((tk>>8) & 255u)
              : (j==2) ? (int)((tk>>16) & 255u) : 255;
        lbf[ks][e] = (short)((f == p) ? 0x3F80 : 0);
      }
  }

  for (int c = 0; c < 7; c++) {
    const int tbase = (half*7 + c) * 16;
    __syncthreads();                    // protect U (Ps of prev chunk)
    // Qg[s][q][b] = sum_i Gs[s][a_i(q)][b]; cols 36..63 zeroed
    for (int idx = tid; idx < 5120; idx += 256) {
      int s = idx >> 10, q = (idx >> 6) & 15, b = idx & 63;
      ushort val = 0;
      if (b < 36) {
        uint tq = tupT[tbase + q];
        int a0 = (int)(tq&255u)*3, a1 = (int)((tq>>8)&255u)*3+1, a2 = (int)((tq>>16)&255u)*3+2;
        val = f2bf(bf2f(GsS[s][a0][b]) + bf2f(GsS[s][a1][b]) + bf2f(GsS[s][a2][b]));
      }
      U.Qg[s][q][b] = val;
    }
    __syncthreads();

    float4 q4r[4];
    #pragma unroll
    for (int r = 0; r < 4; r++) q4r[r] = qstS[c*16 + rowg*4 + r];

    f32x4 acc[5][4];
    #pragma unroll
    for (int s = 0; s < 5; s++) {
      short8 af0 = *(const short8*)&U.Qg[s][col16][rowg*8];
      short8 af1 = *(const short8*)&U.Qg[s][col16][32 + rowg*8];
      #pragma unroll
      for (int i = 0; i < 4; i++) {
        int ntile = wv + 4*i;
        if (ntile < 14) {
          f32x4 a4 = {0.f,0.f,0.f,0.f};
          a4 = __builtin_amdgcn_mfma_f32_16x16x32_bf16(af0, ebf[i][0], a4, 0, 0, 0);
          a4 = __builtin_amdgcn_mfma_f32_16x16x32_bf16(af1, ebf[i][1], a4, 0, 0, 0);
          float4 k4 = kstS[s][ntile*16 + col16];
          #pragma unroll
          for (int r = 0; r < 4; r++) {
            float X = a4[r] - k4.x * q4r[r].z - q4r[r].x * (k4.z - k4.x * Ggh);
            a4[r] = q4r[r].y * k4.y * X + q4r[r].w + k4.w;
          }
          acc[s][i] = a4;
        }
      }
    }

    // softmax over 1120 cols (rows = 16 q-tuples, C-fragment layout)
    float mxr[4] = {-1e30f,-1e30f,-1e30f,-1e30f};
    #pragma unroll
    for (int s = 0; s < 5; s++)
      #pragma unroll
      for (int i = 0; i < 4; i++)
        if (wv + 4*i < 14) {
          #pragma unroll
          for (int r = 0; r < 4; r++) mxr[r] = fmaxf(mxr[r], acc[s][i][r]);
        }
    #pragma unroll
    for (int o = 8; o > 0; o >>= 1) {
      #pragma unroll
      for (int r = 0; r < 4; r++) mxr[r] = fmaxf(mxr[r], __shfl_xor(mxr[r], o));
    }
    if (col16 == 0) {
      #pragma unroll
      for (int r = 0; r < 4; r++) red[wv][rowg*4 + r] = mxr[r];
    }
    __syncthreads();
    float mxg[4];
    #pragma unroll
    for (int r = 0; r < 4; r++) {
      int row = rowg*4 + r;
      mxg[r] = fmaxf(fmaxf(red[0][row], red[1][row]), fmaxf(red[2][row], red[3][row]));
    }
    __syncthreads();
    float smr[4] = {0.f,0.f,0.f,0.f};
    #pragma unroll
    for (int s = 0; s < 5; s++)
      #pragma unroll
      for (int i = 0; i < 4; i++)
        if (wv + 4*i < 14) {
          #pragma unroll
          for (int r = 0; r < 4; r++) {
            float p = __expf(acc[s][i][r] - mxg[r]);
            acc[s][i][r] = p;
            smr[r] += p;
          }
        }
    #pragma unroll
    for (int o = 8; o > 0; o >>= 1) {
      #pragma unroll
      for (int r = 0; r < 4; r++) smr[r] += __shfl_xor(smr[r], o);
    }
    if (col16 == 0) {
      #pragma unroll
      for (int r = 0; r < 4; r++) red[wv][rowg*4 + r] = smr[r];
    }
    __syncthreads();
    float inv[4];
    #pragma unroll
    for (int r = 0; r < 4; r++) {
      int row = rowg*4 + r;
      inv[r] = 1.0f / (red[0][row] + red[1][row] + red[2][row] + red[3][row]);
    }

    // per-shot: write P_s (raw exp), marginal MFMA, store normalized M
    #pragma unroll
    for (int s = 0; s < 5; s++) {
      #pragma unroll
      for (int i = 0; i < 4; i++) {
        int ntile = wv + 4*i;
        if (ntile < 14) {
          #pragma unroll
          for (int r = 0; r < 4; r++)
            U.Ps[s & 1][rowg*4 + r][ntile*16 + col16] = f2bf(acc[s][i][r]);
        }
      }
      __syncthreads();
      if (wv < 3) {
        f32x4 macc = {0.f,0.f,0.f,0.f};
        #pragma unroll
        for (int ks = 0; ks < 7; ks++) {
          short8 pa = *(const short8*)&U.Ps[s & 1][col16][ks*32 + rowg*8];
          macc = __builtin_amdgcn_mfma_f32_16x16x32_bf16(pa, lbf[ks], macc, 0, 0, 0);
        }
        int bin = wv*16 + col16;
        if (bin < 36) {
          #pragma unroll
          for (int r = 0; r < 4; r++) {
            int t = tbase + rowg*4 + r;
            if (t < 220)
              Mg[(((size_t)(h*50 + qu)*5 + w)*220 + t)*192 + s*36 + bin] =
                  f2bf(macc[r] * inv[r]);
          }
        }
      }
    }
  }
}

// ---------------- PV GEMM + fused distance: logits -------------------------
__global__ __launch_bounds__(256) void pv_kernel(
    const ushort* __restrict__ Mg, const ushort* __restrict__ Vt,
    const float* __restrict__ Cv, const uint* __restrict__ tupP,
    float* __restrict__ out)
{
  __shared__ __align__(16) ushort As[128][72];
  __shared__ __align__(16) ushort Bs[128][72];
  __shared__ uint tupS[224];
  __shared__ float redL[4][2];
  const int tid = threadIdx.x;
  const int nb = blockIdx.x, mb = blockIdx.y, z = blockIdx.z;
  const int w = z >> 1, h = z & 1;
  const int m0 = mb * 128, n0 = nb * 128;
  const int wv = tid >> 6, lane = tid & 63;
  const int wm = wv >> 1, wn = wv & 1;
  const int rowg = lane >> 4, col16 = lane & 15;
  for (int idx = tid; idx < 224; idx += 256) tupS[idx] = (idx < 220) ? tupP[idx] : 0u;

  f32x4 acc[4][4] = {};
  for (int k0 = 0; k0 < 192; k0 += 64) {
    __syncthreads();
    for (int sidx = tid; sidx < 1024; sidx += 256) {
      int row = sidx >> 3, seg = sidx & 7;
      int gm = m0 + row;
      uint4 va = {0,0,0,0};
      if (gm < 11000) {
        int qu = gm / 220, t = gm - qu * 220;
        va = *(const uint4*)(Mg + (((size_t)(h*50 + qu)*5 + w)*220 + t)*192 + k0 + seg*8);
      }
      *(uint4*)&As[row][seg*8] = va;
      int gn = n0 + row;
      uint4 vb = {0,0,0,0};
      if (gn < 576)
        vb = *(const uint4*)(Vt + ((size_t)z*576 + gn)*192 + k0 + seg*8);
      *(uint4*)&Bs[row][seg*8] = vb;
    }
    __syncthreads();
    #pragma unroll
    for (int ks = 0; ks < 2; ks++) {
      short8 a[4], b[4];
      #pragma unroll
      for (int i = 0; i < 4; i++) {
        a[i] = *(const short8*)&As[wm*64 + i*16 + col16][ks*32 + rowg*8];
        b[i] = *(const short8*)&Bs[wn*64 + i*16 + col16][ks*32 + rowg*8];
      }
      #pragma unroll
      for (int mi = 0; mi < 4; mi++)
        #pragma unroll
        for (int ni = 0; ni < 4; ni++)
          acc[mi][ni] = __builtin_amdgcn_mfma_f32_16x16x32_bf16(a[mi], b[ni], acc[mi][ni], 0, 0, 0);
    }
  }
  // fused distance epilogue
  const int quA = m0 / 220;
  const int mB = (quA + 1) * 220;
  float sq0 = 0.f, sq1 = 0.f;
  #pragma unroll
  for (int mi = 0; mi < 4; mi++) {
    #pragma unroll
    for (int r = 0; r < 4; r++) {
      int m = m0 + wm*64 + mi*16 + rowg*4 + r;
      if (m >= 11000) continue;
      int qu = (m >= mB) ? quA + 1 : quA;
      int t = m - qu * 220;
      uint tq = tupS[t];
      int f0 = (int)(tq & 255u), f1 = (int)((tq>>8) & 255u), f2v = (int)((tq>>16) & 255u);
      const float* c0 = Cv + (size_t)((25+qu)*36 + f0*3 + 0) * DIM + h * HDIM;
      const float* c1 = Cv + (size_t)((25+qu)*36 + f1*3 + 1) * DIM + h * HDIM;
      const float* c2 = Cv + (size_t)((25+qu)*36 + f2v*3 + 2) * DIM + h * HDIM;
      #pragma unroll
      for (int ni = 0; ni < 4; ni++) {
        int n = n0 + wn*64 + ni*16 + col16;
        if (n < 576) {
          float qv = c0[n] + c1[n] + c2[n];
          float d = qv - acc[mi][ni][r];
          float s2 = d * d;
          if (qu == quA) sq0 += s2; else sq1 += s2;
        }
      }
    }
  }
  #pragma unroll
  for (int o = 32; o > 0; o >>= 1) {
    sq0 += __shfl_down(sq0, o);
    sq1 += __shfl_down(sq1, o);
  }
  if (lane == 0) { redL[wv][0] = sq0; redL[wv][1] = sq1; }
  __syncthreads();
  if (tid == 0) {
    float t0 = redL[0][0] + redL[1][0] + redL[2][0] + redL[3][0];
    float t1 = redL[0][1] + redL[1][1] + redL[2][1] + redL[3][1];
    atomicAdd(&out[quA*5 + w], -t0 * (1.0f/220.0f));
    if (quA + 1 < 50 && t1 != 0.f)
      atomicAdd(&out[(quA+1)*5 + w], -t1 * (1.0f/220.0f));
  }
}

// ---------------------------------------------------------------------------
extern "C" void kernel_launch(void* const* d_in, const int* in_sizes, int n_in,
                              void* d_out, int out_size, void* d_ws, size_t ws_size,
                              hipStream_t stream) {
  const float* support = (const float*)d_in[0];
  const float* queries = (const float*)d_in[1];
  // d_in[2] = support_labels (sorted by construction; unused)
  const float* kw = (const float*)d_in[3];
  const float* kb = (const float*)d_in[4];
  const float* vw = (const float*)d_in[5];
  const float* vb = (const float*)d_in[6];
  const float* g  = (const float*)d_in[7];
  const float* bb = (const float*)d_in[8];
  float* out = (float*)d_out;

  float* ws = (float*)d_ws;
  size_t off = 0;
  auto alloc = [&](size_t n) { float* p = ws + off; off += (n + 63) & ~(size_t)63; return p; };
  float* PE   = alloc(12 * DIM);
  // region1: Fb (bf16 900x1152) / Ckw (bf16 2700x1152) / Mg (bf16 500x220x192)
  float* r1   = alloc(10560000);
  ushort* Fb  = (ushort*)r1;
  ushort* Ckw = (ushort*)r1;
  ushort* Mg  = (ushort*)r1;
  // region2: Wt (bf16 6912x1152) / Gb (bf16 2x1800x900)
  float* r2   = alloc(3981312);
  ushort* Wt  = (ushort*)r2;
  ushort* Gb  = (ushort*)r2;
  float* Ck   = alloc((size_t)2700 * DIM);
  float* Cv   = alloc((size_t)2700 * DIM);
  float* m_arr = alloc(2700);
  float* A_arr = alloc(2 * 2700);
  float* B_arr = alloc(2 * 2700);
  float* S     = alloc(75 * 1296);
  float4* kst  = (float4*)alloc(2 * 75 * 220 * 4);
  float* consts = alloc(64);
  int* tup   = (int*)alloc(660);
  uint* tupP = (uint*)alloc(256);
  float* VtF = alloc(552960);          // Vt bf16 [10][576][192]
  ushort* Vt = (ushort*)VtF;

  hipMemsetAsync(d_out, 0, (size_t)out_size * sizeof(float), stream);

  init_tables<<<1, 256, 0, stream>>>(g, bb, tup, tupP, consts);
  pe_kernel<<<(12 * DIM + 255) / 256, 256, 0, stream>>>(PE);
  add_pe_bf<<<(900 * DIM + 255) / 256, 256, 0, stream>>>(support, queries, PE, Fb);
  conv_w<<<dim3(36, 216), 256, 0, stream>>>(kw, vw, Wt);
  gemm_proj_mfma<<<dim3(54, 8), 256, 0, stream>>>(Fb, Wt, kb, vb, Ck, Cv);
  row_stats<<<2700, 128, 0, stream>>>(Ck, g, bb, m_arr, A_arr, B_arr);
  self_gram<<<75, 256, 0, stream>>>(Ck, S);
  row_ln<<<75, 256, 0, stream>>>(S, m_arr, A_arr, B_arr, tup, kst);
  conv_ckw<<<(int)(((size_t)2700 * DIM + 255) / 256), 256, 0, stream>>>(Ck, g, Ckw);
  cross_gram_mfma<<<dim3(8, 15, 2), 256, 0, stream>>>(Ckw, Gb);
  vt_build<<<dim3(9, 10), 256, 0, stream>>>(Cv, Vt);
  hipMemsetAsync(Mg, 0, (size_t)500 * 220 * 192 * 2, stream);
  attn2<<<dim3(2, 5, 100), 256, 0, stream>>>(Gb, kst, tupP, consts, Mg);
  pv_kernel<<<dim3(5, 86, 10), 256, 0, stream>>>(Mg, Vt, Cv, tupP, out);
}

// Round 7
// 866.727 us; speedup vs baseline: 3.0626x; 1.0736x over previous
//
#include <hip/hip_runtime.h>
#include <math.h>

// ---------------------------------------------------------------------------
// MultiTemporalCrossTransformer — factorized algorithm, round 6 (resubmit; r6
// bench was lost to a GPU-acquisition timeout, not a kernel failure).
//   * prep: Fb = bf16(x + PE) with inline fp32 PE; tuple tables + g/b consts
//     via shfl reductions (no shared float atomics)  [was 3 kernels]
//   * projections via bf16 MFMA GEMM (frame-factorized: 900x6912x1152)
//   * LN stats from per-frame means + fp32 self-Gram (K-split x3)
//   * scores: (Eq.Gs).Ek^T associativity -> Qg gather + MFMA vs static 0/1 Ek
//   * marginalization via per-shot MFMA P_s . L^T -> M to global bf16
//     (attn2 also zero-fills M's 12 pad columns; no giant memset)
//   * PV + distance as a batched 128x128x192 MFMA GEMM kernel
// ---------------------------------------------------------------------------

#define DIM 1152
#define HDIM 576
#define NTUP 220

typedef __attribute__((ext_vector_type(4))) float f32x4;
typedef __attribute__((ext_vector_type(8))) short short8;

__device__ __forceinline__ ushort f2bf(float x) {
  union { float f; unsigned u; } v; v.f = x;
  unsigned r = (v.u + 0x7FFFu + ((v.u >> 16) & 1u)) >> 16;
  return (ushort)r;
}
__device__ __forceinline__ float bf2f(ushort x) {
  union { unsigned u; float f; } v; v.u = ((unsigned)x) << 16;
  return v.f;
}

// ---------------- prep: Fb = bf16(x+PE); tables + consts -------------------
__global__ __launch_bounds__(256) void prep(
    const float* __restrict__ sup, const float* __restrict__ qry,
    const float* __restrict__ g, const float* __restrict__ bb,
    ushort* __restrict__ Fb, int* __restrict__ tup, uint* __restrict__ tupP,
    float* __restrict__ consts)
{
  const int tid = threadIdx.x;
  const int b = blockIdx.x;
  if (b < 900) {
    const int p = b % 12;
    const float* src = (b < 300) ? (sup + (size_t)b * DIM)
                                 : (qry + (size_t)(b - 300) * DIM);
    for (int d = tid; d < DIM; d += 256) {
      int j = d >> 1;
      float div = expf((float)(2 * j) * (-9.210340371976184f / 1152.0f));
      float ang = (float)p * div;
      float pe = ((d & 1) ? cosf(ang) : sinf(ang)) * 0.1f;
      Fb[(size_t)b * DIM + d] = f2bf(src[d] + pe);
    }
    return;
  }
  // single table block
  if (tid < 220) {
    int t = tid, idx = 0;
    for (int a = 0; a < 10; a++)
      for (int b2 = a + 1; b2 < 11; b2++)
        for (int c = b2 + 1; c < 12; c++) {
          if (idx == t) {
            tup[t*3+0]=a; tup[t*3+1]=b2; tup[t*3+2]=c;
            tupP[t] = (uint)a | ((uint)b2 << 8) | ((uint)c << 16);
          }
          idx++;
        }
  }
  float s[6] = {0,0,0,0,0,0};
  for (int d = tid; d < DIM; d += 256) {
    float gv = g[d], bv = bb[d];
    int h = (d >= HDIM);
    s[h]     += gv*gv;
    s[2 + h] += gv*bv;
    s[4 + h] += bv*bv;
  }
  __shared__ float red[4][6];
  #pragma unroll
  for (int i = 0; i < 6; i++)
    #pragma unroll
    for (int o = 32; o > 0; o >>= 1) s[i] += __shfl_down(s[i], o);
  if ((tid & 63) == 0) {
    #pragma unroll
    for (int i = 0; i < 6; i++) red[tid >> 6][i] = s[i];
  }
  __syncthreads();
  if (tid < 6) consts[tid] = red[0][tid] + red[1][tid] + red[2][tid] + red[3][tid];
}

// ---------------- W transpose+convert: Wt[n][k] bf16 -----------------------
__global__ __launch_bounds__(256) void conv_w(
    const float* __restrict__ kw, const float* __restrict__ vw,
    ushort* __restrict__ Wt)
{
  __shared__ float tileS[32][33];
  const int tid = threadIdx.x;
  const int kt = blockIdx.x * 32;    // K base
  const int ng0 = blockIdx.y * 32;   // N base (0..6880)
  const int b = ng0 / DIM, d0 = ng0 - b * DIM;
  const float* src = (b < 3) ? (kw + (size_t)b * DIM * DIM)
                             : (vw + (size_t)(b - 3) * DIM * DIM);
  const int r = tid >> 3, cs = (tid & 7) * 4;
  float4 vsrc = *(const float4*)(src + (size_t)(kt + r) * DIM + d0 + cs);
  tileS[r][cs+0] = vsrc.x; tileS[r][cs+1] = vsrc.y;
  tileS[r][cs+2] = vsrc.z; tileS[r][cs+3] = vsrc.w;
  __syncthreads();
  uint u0 = (uint)f2bf(tileS[cs+0][r]) | ((uint)f2bf(tileS[cs+1][r]) << 16);
  uint u1 = (uint)f2bf(tileS[cs+2][r]) | ((uint)f2bf(tileS[cs+3][r]) << 16);
  uint2 o; o.x = u0; o.y = u1;
  *(uint2*)(Wt + (size_t)(ng0 + r) * DIM + kt + cs) = o;
}

// ---------------- projection MFMA GEMM: C[900,6912] = Fb @ Wt^T ------------
__global__ __launch_bounds__(256) void gemm_proj_mfma(
    const ushort* __restrict__ Fb, const ushort* __restrict__ Wt,
    const float* __restrict__ kb, const float* __restrict__ vb,
    float* __restrict__ Ck, float* __restrict__ Cv)
{
  __shared__ __align__(16) ushort As[128][72];
  __shared__ __align__(16) ushort Bs[128][72];
  const int tid = threadIdx.x;
  const int col0 = blockIdx.x * 128;    // 0..6784
  const int row0 = blockIdx.y * 128;    // 0..896
  f32x4 acc[4][4] = {};
  const int wv = tid >> 6, lane = tid & 63;
  const int wm = wv >> 1, wn = wv & 1;
  for (int k0 = 0; k0 < DIM; k0 += 64) {
    __syncthreads();
    for (int sidx = tid; sidx < 1024; sidx += 256) {
      int rowa = sidx >> 3, kseg = sidx & 7;
      uint4 va = {0,0,0,0};
      int gm = row0 + rowa;
      if (gm < 900) va = *(const uint4*)(Fb + (size_t)gm * DIM + k0 + kseg * 8);
      *(uint4*)&As[rowa][kseg * 8] = va;
      int gc = col0 + rowa;
      uint4 vb4 = *(const uint4*)(Wt + (size_t)gc * DIM + k0 + kseg * 8);
      *(uint4*)&Bs[rowa][kseg * 8] = vb4;
    }
    __syncthreads();
    #pragma unroll
    for (int ks = 0; ks < 64; ks += 32) {
      short8 a[4], b[4];
      #pragma unroll
      for (int i = 0; i < 4; i++) {
        a[i] = *(const short8*)&As[wm*64 + i*16 + (lane & 15)][ks + (lane >> 4) * 8];
        b[i] = *(const short8*)&Bs[wn*64 + i*16 + (lane & 15)][ks + (lane >> 4) * 8];
      }
      #pragma unroll
      for (int mi = 0; mi < 4; mi++)
        #pragma unroll
        for (int ni = 0; ni < 4; ni++)
          acc[mi][ni] = __builtin_amdgcn_mfma_f32_16x16x32_bf16(a[mi], b[ni], acc[mi][ni], 0, 0, 0);
    }
  }
  const int b = col0 / DIM, d_base = col0 - b * DIM;
  #pragma unroll
  for (int mi = 0; mi < 4; mi++)
    #pragma unroll
    for (int ni = 0; ni < 4; ni++)
      #pragma unroll
      for (int r = 0; r < 4; r++) {
        int m = row0 + wm * 64 + mi * 16 + (lane >> 4) * 4 + r;
        if (m >= 900) continue;
        int n = wn * 64 + ni * 16 + (lane & 15);
        int d = d_base + n;
        float val = acc[mi][ni][r];
        if (b < 3) Ck[((size_t)m * 3 + b)       * DIM + d] = val + kb[d] * (1.f/3.f);
        else       Cv[((size_t)m * 3 + (b - 3)) * DIM + d] = val + vb[d] * (1.f/3.f);
      }
}

// ---------------- per frame-projection row stats (fp32) --------------------
__global__ __launch_bounds__(128) void row_stats(
    const float* __restrict__ Ck, const float* __restrict__ g,
    const float* __restrict__ bb, float* __restrict__ m_o,
    float* __restrict__ A_o, float* __restrict__ B_o)
{
  const int r = blockIdx.x, tid = threadIdx.x;
  const float* x = Ck + (size_t)r * DIM;
  float sm = 0, sa0 = 0, sa1 = 0, sb0 = 0, sb1 = 0;
  for (int d = tid; d < DIM; d += 128) {
    float xv = x[d], gv = g[d], bv = bb[d];
    float xg2 = xv * gv * gv, xgb = xv * gv * bv;
    if (d < HDIM) { sa0 += xg2; sb0 += xgb; } else { sa1 += xg2; sb1 += xgb; }
    sm += xv;
  }
  for (int o = 32; o > 0; o >>= 1) {
    sm  += __shfl_down(sm, o);  sa0 += __shfl_down(sa0, o); sa1 += __shfl_down(sa1, o);
    sb0 += __shfl_down(sb0, o); sb1 += __shfl_down(sb1, o);
  }
  __shared__ float red[2][5];
  if ((tid & 63) == 0) {
    int wv = tid >> 6;
    red[wv][0]=sm; red[wv][1]=sa0; red[wv][2]=sa1; red[wv][3]=sb0; red[wv][4]=sb1;
  }
  __syncthreads();
  if (tid == 0) {
    m_o[r]         = (red[0][0] + red[1][0]) * (1.f / 1152.f);
    A_o[r]         =  red[0][1] + red[1][1];
    A_o[2700 + r]  =  red[0][2] + red[1][2];
    B_o[r]         =  red[0][3] + red[1][3];
    B_o[2700 + r]  =  red[0][4] + red[1][4];
  }
}

// ---------------- per-sequence 36x36 self-Gram, K-split x3 -----------------
__global__ __launch_bounds__(256) void self_gram(
    const float* __restrict__ Ck, float* __restrict__ S)
{
  const int u = blockIdx.x, part = blockIdx.y, tid = threadIdx.x;
  __shared__ float CS[36][129];
  float acc[2][3] = {{0,0,0},{0,0,0}};
  const int ta = tid / 12, tb = tid - (tid / 12) * 12;
  const int kbase = part * 384;
  for (int k0 = kbase; k0 < kbase + 384; k0 += 128) {
    __syncthreads();
    for (int idx = tid; idx < 36 * 128; idx += 256) {
      int rr = idx >> 7, kk = idx & 127;
      CS[rr][kk] = Ck[((size_t)u * 36 + rr) * DIM + k0 + kk];
    }
    __syncthreads();
    if (ta < 18) {
      for (int kk = 0; kk < 128; kk++) {
        float va0 = CS[ta*2][kk], va1 = CS[ta*2+1][kk];
        float vb0 = CS[tb*3][kk], vb1 = CS[tb*3+1][kk], vb2 = CS[tb*3+2][kk];
        acc[0][0]+=va0*vb0; acc[0][1]+=va0*vb1; acc[0][2]+=va0*vb2;
        acc[1][0]+=va1*vb0; acc[1][1]+=va1*vb1; acc[1][2]+=va1*vb2;
      }
    }
  }
  if (ta < 18) {
    #pragma unroll
    for (int i = 0; i < 2; i++)
      #pragma unroll
      for (int j = 0; j < 3; j++)
        S[((size_t)part * 75 + u) * 1296 + (ta*2+i) * 36 + tb*3+j] = acc[i][j];
  }
}

// ---------------- per-(seq,tuple) LN stats packed: kst[2][75][220] ---------
__global__ __launch_bounds__(256) void row_ln(
    const float* __restrict__ S, const float* __restrict__ m_i,
    const float* __restrict__ A_i, const float* __restrict__ B_i,
    const int* __restrict__ tup, float4* __restrict__ kst)
{
  const int u = blockIdx.x, tid = threadIdx.x;
  __shared__ float Ss[36][36];
  __shared__ float ms[36], As[2][36], Bs[2][36];
  for (int idx = tid; idx < 1296; idx += 256)
    (&Ss[0][0])[idx] = S[(size_t)u * 1296 + idx]
                     + S[(size_t)(75 + u) * 1296 + idx]
                     + S[(size_t)(150 + u) * 1296 + idx];
  if (tid < 36) {
    ms[tid]    = m_i[u * 36 + tid];
    As[0][tid] = A_i[u * 36 + tid];  As[1][tid] = A_i[2700 + u * 36 + tid];
    Bs[0][tid] = B_i[u * 36 + tid];  Bs[1][tid] = B_i[2700 + u * 36 + tid];
  }
  __syncthreads();
  if (tid < NTUP) {
    int a0 = tup[tid*3+0]*3+0, a1 = tup[tid*3+1]*3+1, a2 = tup[tid*3+2]*3+2;
    float mu = ms[a0] + ms[a1] + ms[a2];
    float qq = Ss[a0][a0] + Ss[a1][a1] + Ss[a2][a2]
             + 2.f * (Ss[a0][a1] + Ss[a0][a2] + Ss[a1][a2]);
    float var = qq * (1.f / 1152.f) - mu * mu;
    float rr = rsqrtf(var + 1e-5f);
    kst[((size_t)0 * 75 + u) * 220 + tid] =
        make_float4(mu, rr, As[0][a0]+As[0][a1]+As[0][a2], Bs[0][a0]+Bs[0][a1]+Bs[0][a2]);
    kst[((size_t)1 * 75 + u) * 220 + tid] =
        make_float4(mu, rr, As[1][a0]+As[1][a1]+As[1][a2], Bs[1][a0]+Bs[1][a1]+Bs[1][a2]);
  }
}

// ---------------- Ckw = bf16(Ck * g) ---------------------------------------
__global__ __launch_bounds__(256) void conv_ckw(
    const float* __restrict__ Ck, const float* __restrict__ g,
    ushort* __restrict__ Ckw)
{
  size_t i = (size_t)blockIdx.x * 256 + threadIdx.x;
  if (i >= (size_t)2700 * DIM) return;
  int d = (int)(i % DIM);
  Ckw[i] = f2bf(Ck[i] * g[d]);
}

// ---------------- cross-Gram MFMA: Gb[h][1800][900] bf16 -------------------
__global__ __launch_bounds__(256) void cross_gram_mfma(
    const ushort* __restrict__ Ckw, ushort* __restrict__ Gb)
{
  __shared__ __align__(16) ushort As[128][72];
  __shared__ __align__(16) ushort Bs[128][72];
  const int tid = threadIdx.x;
  const int col0 = blockIdx.x * 128;   // N=900
  const int row0 = blockIdx.y * 128;   // M=1800
  const int h = blockIdx.z;
  f32x4 acc[4][4] = {};
  const int wv = tid >> 6, lane = tid & 63;
  const int wm = wv >> 1, wn = wv & 1;
  for (int k0 = 0; k0 < HDIM; k0 += 64) {
    __syncthreads();
    for (int sidx = tid; sidx < 1024; sidx += 256) {
      int rowa = sidx >> 3, kseg = sidx & 7;
      uint4 va = {0,0,0,0};
      int gm = row0 + rowa;
      if (gm < 1800)
        va = *(const uint4*)(Ckw + (size_t)(900 + gm) * DIM + h * HDIM + k0 + kseg * 8);
      *(uint4*)&As[rowa][kseg * 8] = va;
      uint4 vb = {0,0,0,0};
      int gn = col0 + rowa;
      if (gn < 900)
        vb = *(const uint4*)(Ckw + (size_t)gn * DIM + h * HDIM + k0 + kseg * 8);
      *(uint4*)&Bs[rowa][kseg * 8] = vb;
    }
    __syncthreads();
    #pragma unroll
    for (int ks = 0; ks < 64; ks += 32) {
      short8 a[4], b[4];
      #pragma unroll
      for (int i = 0; i < 4; i++) {
        a[i] = *(const short8*)&As[wm*64 + i*16 + (lane & 15)][ks + (lane >> 4) * 8];
        b[i] = *(const short8*)&Bs[wn*64 + i*16 + (lane & 15)][ks + (lane >> 4) * 8];
      }
      #pragma unroll
      for (int mi = 0; mi < 4; mi++)
        #pragma unroll
        for (int ni = 0; ni < 4; ni++)
          acc[mi][ni] = __builtin_amdgcn_mfma_f32_16x16x32_bf16(a[mi], b[ni], acc[mi][ni], 0, 0, 0);
    }
  }
  #pragma unroll
  for (int mi = 0; mi < 4; mi++)
    #pragma unroll
    for (int ni = 0; ni < 4; ni++)
      #pragma unroll
      for (int r = 0; r < 4; r++) {
        int m = row0 + wm * 64 + mi * 16 + (lane >> 4) * 4 + r;
        int n = col0 + wn * 64 + ni * 16 + (lane & 15);
        if (m < 1800 && n < 900)
          Gb[((size_t)h * 1800 + m) * 900 + n] = f2bf(acc[mi][ni][r]);
      }
}

// ---------------- Vt[w*2+h][d=576][k=192] bf16 (transposed V, K-padded) ----
__global__ __launch_bounds__(256) void vt_build(
    const float* __restrict__ Cv, ushort* __restrict__ Vt)
{
  __shared__ ushort T[192][72];
  const int tid = threadIdx.x;
  const int nb = blockIdx.x, z = blockIdx.y;
  const int w = z >> 1, h = z & 1;
  const int n0 = nb * 64;
  for (int idx = tid; idx < 12288; idx += 256) {
    int bin = idx >> 6, nc = idx & 63;
    ushort v = 0;
    if (bin < 180) {
      int s = bin / 36, rem = bin - s * 36, j = rem / 12, p = rem - j * 12;
      v = f2bf(Cv[(size_t)((w*5+s)*36 + p*3 + j) * DIM + h * HDIM + n0 + nc]);
    }
    T[bin][nc] = v;
  }
  __syncthreads();
  for (int u4i = tid; u4i < 1536; u4i += 256) {
    int n = u4i / 24, kc = (u4i - n * 24) * 8;
    ushort tmp[8];
    #pragma unroll
    for (int e = 0; e < 8; e++) tmp[e] = T[kc + e][n];
    *(uint4*)(Vt + ((size_t)z * 576 + n0 + n) * 192 + kc) = *(uint4*)tmp;
  }
}

// ---------------- attn2: scores + softmax + marginal -> Mg -----------------
__global__ __launch_bounds__(256) void attn2(
    const ushort* __restrict__ Gb, const float4* __restrict__ kst,
    const uint* __restrict__ tupP, const float* __restrict__ consts,
    ushort* __restrict__ Mg)
{
  __shared__ __align__(16) ushort GsS[5][36][36];
  __shared__ __align__(16) float4 kstS[5][224];
  __shared__ __align__(16) union UU { ushort Qg[5][16][64]; ushort Ps[2][16][224]; } U;
  __shared__ __align__(16) float4 qstS[112];
  __shared__ uint tupT[224];
  __shared__ float red[4][16];

  const int tid = threadIdx.x;
  const int half = blockIdx.x, w = blockIdx.y;
  const int qu = blockIdx.z >> 1, h = blockIdx.z & 1;
  const float Ggh = consts[h], Gbh = consts[2 + h], Bbh = consts[4 + h];
  const int wv = tid >> 6, lane = tid & 63;
  const int rowg = lane >> 4, col16 = lane & 15;

  for (int idx = tid; idx < 224; idx += 256) tupT[idx] = (idx < 220) ? tupP[idx] : 0u;
  for (int idx = tid; idx < 3240; idx += 256) {
    int s = idx / 648, rem = idx - s * 648, a = rem / 18, bp = rem - a * 18;
    ((uint*)&GsS[s][a][0])[bp] =
      *(const uint*)(Gb + (size_t)(h*1800 + qu*36 + a) * 900 + (w*5+s)*36 + bp*2);
  }
  for (int idx = tid; idx < 1120; idx += 256) {
    int s = idx / 224, k = idx - s * 224;
    float4 v;
    if (k < 220) {
      float4 t4 = kst[((size_t)h*75 + w*5 + s) * 220 + k];
      v = make_float4(t4.x, t4.y, t4.z, (t4.y*(t4.w - t4.x*Gbh) + Bbh) * (1.f/24.f));
    } else v = make_float4(0.f, 0.f, 0.f, -1e30f);
    kstS[s][k] = v;
  }
  for (int idx = tid; idx < 112; idx += 256) {
    int t = half * 112 + idx;
    float4 v = make_float4(0.f, 0.f, 0.f, 0.f);
    if (t < 220) {
      float4 q4 = kst[((size_t)h*75 + 25 + qu) * 220 + t];
      v = make_float4(q4.x, q4.y * (1.f/24.f), q4.z,
                      q4.y * (q4.w - q4.x*Gbh) * (1.f/24.f));
    }
    qstS[idx] = v;
  }
  __syncthreads();

  // static Ek B-fragments (score MFMA), synthesized in registers
  short8 ebf[4][2];
  #pragma unroll
  for (int i = 0; i < 4; i++) {
    int ntile = wv + 4*i;
    uint tk = tupT[ntile*16 + col16];
    int b0 = (int)(tk & 255u)*3, b1 = (int)((tk>>8)&255u)*3+1, b2 = (int)((tk>>16)&255u)*3+2;
    #pragma unroll
    for (int ks = 0; ks < 2; ks++)
      #pragma unroll
      for (int e = 0; e < 8; e++) {
        int colb = ks*32 + rowg*8 + e;
        ebf[i][ks][e] = (short)((colb==b0 || colb==b1 || colb==b2) ? 0x3F80 : 0);
      }
  }
  // static L^T B-fragments (marginal MFMA), waves 0..2 own bin-tile = wv
  short8 lbf[7];
  {
    int bin = wv*16 + col16;
    int j = bin / 12, p = bin - j*12;
    #pragma unroll
    for (int ks = 0; ks < 7; ks++)
      #pragma unroll
      for (int e = 0; e < 8; e++) {
        int k = ks*32 + rowg*8 + e;
        uint tk = tupT[k];
        int f = (j==0) ? (int)(tk & 255u) : (j==1) ? (int)((tk>>8) & 255u)
              : (j==2) ? (int)((tk>>16) & 255u) : 255;
        lbf[ks][e] = (short)((f == p) ? 0x3F80 : 0);
      }
  }

  for (int c = 0; c < 7; c++) {
    const int tbase = (half*7 + c) * 16;
    __syncthreads();                    // protect U (Ps of prev chunk)
    // Qg[s][q][b] = sum_i Gs[s][a_i(q)][b]; cols 36..63 zeroed
    for (int idx = tid; idx < 5120; idx += 256) {
      int s = idx >> 10, q = (idx >> 6) & 15, b = idx & 63;
      ushort val = 0;
      if (b < 36) {
        uint tq = tupT[tbase + q];
        int a0 = (int)(tq&255u)*3, a1 = (int)((tq>>8)&255u)*3+1, a2 = (int)((tq>>16)&255u)*3+2;
        val = f2bf(bf2f(GsS[s][a0][b]) + bf2f(GsS[s][a1][b]) + bf2f(GsS[s][a2][b]));
      }
      U.Qg[s][q][b] = val;
    }
    __syncthreads();

    float4 q4r[4];
    #pragma unroll
    for (int r = 0; r < 4; r++) q4r[r] = qstS[c*16 + rowg*4 + r];

    f32x4 acc[5][4];
    #pragma unroll
    for (int s = 0; s < 5; s++) {
      short8 af0 = *(const short8*)&U.Qg[s][col16][rowg*8];
      short8 af1 = *(const short8*)&U.Qg[s][col16][32 + rowg*8];
      #pragma unroll
      for (int i = 0; i < 4; i++) {
        int ntile = wv + 4*i;
        if (ntile < 14) {
          f32x4 a4 = {0.f,0.f,0.f,0.f};
          a4 = __builtin_amdgcn_mfma_f32_16x16x32_bf16(af0, ebf[i][0], a4, 0, 0, 0);
          a4 = __builtin_amdgcn_mfma_f32_16x16x32_bf16(af1, ebf[i][1], a4, 0, 0, 0);
          float4 k4 = kstS[s][ntile*16 + col16];
          #pragma unroll
          for (int r = 0; r < 4; r++) {
            float X = a4[r] - k4.x * q4r[r].z - q4r[r].x * (k4.z - k4.x * Ggh);
            a4[r] = q4r[r].y * k4.y * X + q4r[r].w + k4.w;
          }
          acc[s][i] = a4;
        }
      }
    }

    // softmax over 1120 cols (rows = 16 q-tuples, C-fragment layout)
    float mxr[4] = {-1e30f,-1e30f,-1e30f,-1e30f};
    #pragma unroll
    for (int s = 0; s < 5; s++)
      #pragma unroll
      for (int i = 0; i < 4; i++)
        if (wv + 4*i < 14) {
          #pragma unroll
          for (int r = 0; r < 4; r++) mxr[r] = fmaxf(mxr[r], acc[s][i][r]);
        }
    #pragma unroll
    for (int o = 8; o > 0; o >>= 1) {
      #pragma unroll
      for (int r = 0; r < 4; r++) mxr[r] = fmaxf(mxr[r], __shfl_xor(mxr[r], o));
    }
    if (col16 == 0) {
      #pragma unroll
      for (int r = 0; r < 4; r++) red[wv][rowg*4 + r] = mxr[r];
    }
    __syncthreads();
    float mxg[4];
    #pragma unroll
    for (int r = 0; r < 4; r++) {
      int row = rowg*4 + r;
      mxg[r] = fmaxf(fmaxf(red[0][row], red[1][row]), fmaxf(red[2][row], red[3][row]));
    }
    __syncthreads();
    float smr[4] = {0.f,0.f,0.f,0.f};
    #pragma unroll
    for (int s = 0; s < 5; s++)
      #pragma unroll
      for (int i = 0; i < 4; i++)
        if (wv + 4*i < 14) {
          #pragma unroll
          for (int r = 0; r < 4; r++) {
            float p = __expf(acc[s][i][r] - mxg[r]);
            acc[s][i][r] = p;
            smr[r] += p;
          }
        }
    #pragma unroll
    for (int o = 8; o > 0; o >>= 1) {
      #pragma unroll
      for (int r = 0; r < 4; r++) smr[r] += __shfl_xor(smr[r], o);
    }
    if (col16 == 0) {
      #pragma unroll
      for (int r = 0; r < 4; r++) red[wv][rowg*4 + r] = smr[r];
    }
    __syncthreads();
    float inv[4];
    #pragma unroll
    for (int r = 0; r < 4; r++) {
      int row = rowg*4 + r;
      inv[r] = 1.0f / (red[0][row] + red[1][row] + red[2][row] + red[3][row]);
    }

    // per-shot: write P_s (raw exp), marginal MFMA, store normalized M
    #pragma unroll
    for (int s = 0; s < 5; s++) {
      #pragma unroll
      for (int i = 0; i < 4; i++) {
        int ntile = wv + 4*i;
        if (ntile < 14) {
          #pragma unroll
          for (int r = 0; r < 4; r++)
            U.Ps[s & 1][rowg*4 + r][ntile*16 + col16] = f2bf(acc[s][i][r]);
        }
      }
      __syncthreads();
      if (wv < 3) {
        f32x4 macc = {0.f,0.f,0.f,0.f};
        #pragma unroll
        for (int ks = 0; ks < 7; ks++) {
          short8 pa = *(const short8*)&U.Ps[s & 1][col16][ks*32 + rowg*8];
          macc = __builtin_amdgcn_mfma_f32_16x16x32_bf16(pa, lbf[ks], macc, 0, 0, 0);
        }
        int bin = wv*16 + col16;
        if (bin < 36) {
          #pragma unroll
          for (int r = 0; r < 4; r++) {
            int t = tbase + rowg*4 + r;
            if (t < 220)
              Mg[(((size_t)(h*50 + qu)*5 + w)*220 + t)*192 + s*36 + bin] =
                  f2bf(macc[r] * inv[r]);
          }
        }
      }
    }
    // zero-fill pad columns 180..191 for this chunk's rows (replaces memset)
    if (tid < 96) {
      int q = tid / 6, cp = tid - (tid / 6) * 6;
      int t = tbase + q;
      if (t < 220)
        *(uint*)&Mg[(((size_t)(h*50 + qu)*5 + w)*220 + t)*192 + 180 + cp*2] = 0u;
    }
  }
}

// ---------------- PV GEMM + fused distance: logits -------------------------
__global__ __launch_bounds__(256) void pv_kernel(
    const ushort* __restrict__ Mg, const ushort* __restrict__ Vt,
    const float* __restrict__ Cv, const uint* __restrict__ tupP,
    float* __restrict__ out)
{
  __shared__ __align__(16) ushort As[128][72];
  __shared__ __align__(16) ushort Bs[128][72];
  __shared__ uint tupS[224];
  __shared__ float redL[4][2];
  const int tid = threadIdx.x;
  const int nb = blockIdx.x, mb = blockIdx.y, z = blockIdx.z;
  const int w = z >> 1, h = z & 1;
  const int m0 = mb * 128, n0 = nb * 128;
  const int wv = tid >> 6, lane = tid & 63;
  const int wm = wv >> 1, wn = wv & 1;
  const int rowg = lane >> 4, col16 = lane & 15;
  for (int idx = tid; idx < 224; idx += 256) tupS[idx] = (idx < 220) ? tupP[idx] : 0u;

  f32x4 acc[4][4] = {};
  for (int k0 = 0; k0 < 192; k0 += 64) {
    __syncthreads();
    for (int sidx = tid; sidx < 1024; sidx += 256) {
      int row = sidx >> 3, seg = sidx & 7;
      int gm = m0 + row;
      uint4 va = {0,0,0,0};
      if (gm < 11000) {
        int qu = gm / 220, t = gm - qu * 220;
        va = *(const uint4*)(Mg + (((size_t)(h*50 + qu)*5 + w)*220 + t)*192 + k0 + seg*8);
      }
      *(uint4*)&As[row][seg*8] = va;
      int gn = n0 + row;
      uint4 vb = {0,0,0,0};
      if (gn < 576)
        vb = *(const uint4*)(Vt + ((size_t)z*576 + gn)*192 + k0 + seg*8);
      *(uint4*)&Bs[row][seg*8] = vb;
    }
    __syncthreads();
    #pragma unroll
    for (int ks = 0; ks < 2; ks++) {
      short8 a[4], b[4];
      #pragma unroll
      for (int i = 0; i < 4; i++) {
        a[i] = *(const short8*)&As[wm*64 + i*16 + col16][ks*32 + rowg*8];
        b[i] = *(const short8*)&Bs[wn*64 + i*16 + col16][ks*32 + rowg*8];
      }
      #pragma unroll
      for (int mi = 0; mi < 4; mi++)
        #pragma unroll
        for (int ni = 0; ni < 4; ni++)
          acc[mi][ni] = __builtin_amdgcn_mfma_f32_16x16x32_bf16(a[mi], b[ni], acc[mi][ni], 0, 0, 0);
    }
  }
  // fused distance epilogue
  const int quA = m0 / 220;
  const int mB = (quA + 1) * 220;
  float sq0 = 0.f, sq1 = 0.f;
  #pragma unroll
  for (int mi = 0; mi < 4; mi++) {
    #pragma unroll
    for (int r = 0; r < 4; r++) {
      int m = m0 + wm*64 + mi*16 + rowg*4 + r;
      if (m >= 11000) continue;
      int qu = (m >= mB) ? quA + 1 : quA;
      int t = m - qu * 220;
      uint tq = tupS[t];
      int f0 = (int)(tq & 255u), f1 = (int)((tq>>8) & 255u), f2v = (int)((tq>>16) & 255u);
      const float* c0 = Cv + (size_t)((25+qu)*36 + f0*3 + 0) * DIM + h * HDIM;
      const float* c1 = Cv + (size_t)((25+qu)*36 + f1*3 + 1) * DIM + h * HDIM;
      const float* c2 = Cv + (size_t)((25+qu)*36 + f2v*3 + 2) * DIM + h * HDIM;
      #pragma unroll
      for (int ni = 0; ni < 4; ni++) {
        int n = n0 + wn*64 + ni*16 + col16;
        if (n < 576) {
          float qv = c0[n] + c1[n] + c2[n];
          float d = qv - acc[mi][ni][r];
          float s2 = d * d;
          if (qu == quA) sq0 += s2; else sq1 += s2;
        }
      }
    }
  }
  #pragma unroll
  for (int o = 32; o > 0; o >>= 1) {
    sq0 += __shfl_down(sq0, o);
    sq1 += __shfl_down(sq1, o);
  }
  if (lane == 0) { redL[wv][0] = sq0; redL[wv][1] = sq1; }
  __syncthreads();
  if (tid == 0) {
    float t0 = redL[0][0] + redL[1][0] + redL[2][0] + redL[3][0];
    float t1 = redL[0][1] + redL[1][1] + redL[2][1] + redL[3][1];
    atomicAdd(&out[quA*5 + w], -t0 * (1.0f/220.0f));
    if (quA + 1 < 50 && t1 != 0.f)
      atomicAdd(&out[(quA+1)*5 + w], -t1 * (1.0f/220.0f));
  }
}

// ---------------------------------------------------------------------------
extern "C" void kernel_launch(void* const* d_in, const int* in_sizes, int n_in,
                              void* d_out, int out_size, void* d_ws, size_t ws_size,
                              hipStream_t stream) {
  const float* support = (const float*)d_in[0];
  const float* queries = (const float*)d_in[1];
  // d_in[2] = support_labels (sorted by construction; unused)
  const float* kw = (const float*)d_in[3];
  const float* kb = (const float*)d_in[4];
  const float* vw = (const float*)d_in[5];
  const float* vb = (const float*)d_in[6];
  const float* g  = (const float*)d_in[7];
  const float* bb = (const float*)d_in[8];
  float* out = (float*)d_out;

  float* ws = (float*)d_ws;
  size_t off = 0;
  auto alloc = [&](size_t n) { float* p = ws + off; off += (n + 63) & ~(size_t)63; return p; };
  // region1: Fb (bf16 900x1152) / Ckw (bf16 2700x1152) / Mg (bf16 500x220x192)
  float* r1   = alloc(10560000);
  ushort* Fb  = (ushort*)r1;
  ushort* Ckw = (ushort*)r1;
  ushort* Mg  = (ushort*)r1;
  // region2: Wt (bf16 6912x1152) / Gb (bf16 2x1800x900)
  float* r2   = alloc(3981312);
  ushort* Wt  = (ushort*)r2;
  ushort* Gb  = (ushort*)r2;
  float* Ck   = alloc((size_t)2700 * DIM);
  float* Cv   = alloc((size_t)2700 * DIM);
  float* m_arr = alloc(2700);
  float* A_arr = alloc(2 * 2700);
  float* B_arr = alloc(2 * 2700);
  float* S     = alloc(3 * 75 * 1296);
  float4* kst  = (float4*)alloc(2 * 75 * 220 * 4);
  float* consts = alloc(64);
  int* tup   = (int*)alloc(660);
  uint* tupP = (uint*)alloc(256);
  float* VtF = alloc(552960);          // Vt bf16 [10][576][192]
  ushort* Vt = (ushort*)VtF;

  hipMemsetAsync(d_out, 0, (size_t)out_size * sizeof(float), stream);

  prep<<<901, 256, 0, stream>>>(support, queries, g, bb, Fb, tup, tupP, consts);
  conv_w<<<dim3(36, 216), 256, 0, stream>>>(kw, vw, Wt);
  gemm_proj_mfma<<<dim3(54, 8), 256, 0, stream>>>(Fb, Wt, kb, vb, Ck, Cv);
  row_stats<<<2700, 128, 0, stream>>>(Ck, g, bb, m_arr, A_arr, B_arr);
  self_gram<<<dim3(75, 3), 256, 0, stream>>>(Ck, S);
  row_ln<<<75, 256, 0, stream>>>(S, m_arr, A_arr, B_arr, tup, kst);
  conv_ckw<<<(int)(((size_t)2700 * DIM + 255) / 256), 256, 0, stream>>>(Ck, g, Ckw);
  cross_gram_mfma<<<dim3(8, 15, 2), 256, 0, stream>>>(Ckw, Gb);
  vt_build<<<dim3(9, 10), 256, 0, stream>>>(Cv, Vt);
  attn2<<<dim3(2, 5, 100), 256, 0, stream>>>(Gb, kst, tupP, consts, Mg);
  pv_kernel<<<dim3(5, 86, 10), 256, 0, stream>>>(Mg, Vt, Cv, tupP, out);
}